// Round 11
// baseline (260.010 us; speedup 1.0000x reference)
//
#include <hip/hip_runtime.h>
#include <hip/hip_bf16.h>
#include <stdint.h>

#define H 2048
#define L 16
#define D 128
#define NH 32
#define NKV 8
#define SL 32768
#define T_TOT 2064
#define EPS 1e-6f
#define SCALE 0.08838834764831845f
#define NCHUNK 96

typedef __bf16 bf16x8 __attribute__((ext_vector_type(8)));
typedef float f32x4 __attribute__((ext_vector_type(4)));

__device__ __forceinline__ float bf2f(unsigned short u) {
  union { uint32_t i; float f; } v; v.i = ((uint32_t)u) << 16; return v.f;
}
__device__ __forceinline__ unsigned short f2bf(float f) {
  union { float f; uint32_t i; } v; v.f = f;
  uint32_t u = v.i;
  return (unsigned short)((u + 0x7FFFu + ((u >> 16) & 1u)) >> 16);
}
__device__ __forceinline__ void ld8f(const float* p, float* o) {
  float4 a = *(const float4*)p;
  float4 b = *(const float4*)(p + 4);
  o[0]=a.x; o[1]=a.y; o[2]=a.z; o[3]=a.w;
  o[4]=b.x; o[5]=b.y; o[6]=b.z; o[7]=b.w;
}
__device__ __forceinline__ void st8lds(unsigned short* d, const float* v) {
  unsigned short t[8];
#pragma unroll
  for (int j = 0; j < 8; ++j) t[j] = f2bf(v[j]);
  *(uint4*)d = *(const uint4*)t;
}
__device__ __forceinline__ void gl_lds16(const void* g, void* l) {
  __builtin_amdgcn_global_load_lds(
      (const __attribute__((address_space(1))) void*)g,
      (__attribute__((address_space(3))) void*)l, 16, 0, 0);
}

// ---------- f32 -> bf16 conversion (only multi-read tensors: wk, wv, x_ctx, x) ----------
__global__ void k_conv(const float* __restrict__ wk, const float* __restrict__ wv,
                       const float* __restrict__ x_ctx, const float* __restrict__ x,
                       unsigned short* __restrict__ wk_bf, unsigned short* __restrict__ wv_bf,
                       unsigned short* __restrict__ xc_bf) {
  size_t li = (size_t)blockIdx.x * 256 + threadIdx.x;
  const float* src; unsigned short* dst;
  if (li < 262144) { src = wk; dst = wk_bf; }
  else if ((li -= 262144) < 262144) { src = wv; dst = wv_bf; }
  else if ((li -= 262144) < 524288) { src = x_ctx; dst = xc_bf; }
  else if ((li -= 524288) < 4096) { src = x; dst = xc_bf + (size_t)2048 * H; }
  else return;
  float v8[8];
  ld8f(src + li * 8, v8);
  unsigned short t[8];
#pragma unroll
  for (int j = 0; j < 8; ++j) t[j] = f2bf(v8[j]);
  *(uint4*)(dst + li * 8) = *(const uint4*)t;
}

// ---------- Q projection: wq read f32 directly (use-once), reg-staged to bf16 LDS ----------
__launch_bounds__(256)
__global__ void k_q_proj(const unsigned short* __restrict__ xq_bf,
                         const float* __restrict__ wq,
                         float* __restrict__ qpart) {
  const int h = blockIdx.x, s = blockIdx.y;
  const int tid = threadIdx.x, lane = tid & 63, w = tid >> 6;
  __shared__ __align__(16) unsigned char Asm[2048];
  __shared__ __align__(16) unsigned char Bsm[16384];
  f32x4 zf = {0.f, 0.f, 0.f, 0.f};
  f32x4 acc[2] = {zf, zf};
  for (int kt = 0; kt < 2; ++kt) {
    if (w < 2) {
      int sl = w * 64 + lane;
      gl_lds16(xq_bf + (size_t)(sl >> 3) * H + s * 128 + kt * 64 + (sl & 7) * 8, Asm + w * 1024);
    }
#pragma unroll
    for (int q = 0; q < 4; ++q) {
      int sl = (w * 4 + q) * 64 + lane;
      int row = sl >> 3, c0 = (sl & 7) * 8;
      float v8[8];
      ld8f(wq + (size_t)(h * 128 + row) * H + s * 128 + kt * 64 + c0, v8);
      st8lds((unsigned short*)Bsm + row * 64 + c0, v8);
    }
    __syncthreads();
#pragma unroll
    for (int ks = 0; ks < 2; ++ks) {
      bf16x8 a = *(const bf16x8*)(Asm + (lane & 15) * 128 + ks * 64 + (lane >> 4) * 16);
#pragma unroll
      for (int j = 0; j < 2; ++j) {
        int nr = w * 32 + j * 16 + (lane & 15);
        bf16x8 b = *(const bf16x8*)(Bsm + nr * 128 + ks * 64 + (lane >> 4) * 16);
        acc[j] = __builtin_amdgcn_mfma_f32_16x16x32_bf16(a, b, acc[j], 0, 0, 0);
      }
    }
    __syncthreads();
  }
#pragma unroll
  for (int j = 0; j < 2; ++j)
#pragma unroll
    for (int e = 0; e < 4; ++e) {
      int lq = (lane >> 4) * 4 + e;
      int col = w * 32 + j * 16 + (lane & 15);
      qpart[((size_t)(s * NH + h) * L + lq) * D + col] = acc[j][e];
    }
}

// ---------- Q finalize ----------
__global__ void k_q_fin(const float* __restrict__ qpart, const float* __restrict__ qn_w,
                        const float* __restrict__ cos_q, const float* __restrict__ sin_q,
                        unsigned short* __restrict__ qbf) {
  const int head = blockIdx.x >> 4;
  const int l = blockIdx.x & 15;
  const int d = threadIdx.x;
  __shared__ float ybuf[128];
  __shared__ float red[4];
  float v = 0;
  for (int s = 0; s < 16; ++s) v += qpart[((size_t)(s * NH + head) * L + l) * D + d];
  float s1 = v, s2 = v * v;
  for (int m = 1; m < 64; m <<= 1) { s1 += __shfl_xor(s1, m); s2 += __shfl_xor(s2, m); }
  if ((threadIdx.x & 63) == 0) { red[(threadIdx.x >> 6) * 2] = s1; red[(threadIdx.x >> 6) * 2 + 1] = s2; }
  __syncthreads();
  float sum = red[0] + red[2], sumsq = red[1] + red[3];
  float mean = sum * (1.0f / 128.0f);
  float var = sumsq * (1.0f / 128.0f) - mean * mean;
  float rs = rsqrtf(fmaxf(var, 0.f) + EPS);
  float z = (v - mean) * rs * qn_w[d];
  ybuf[d] = z;
  __syncthreads();
  float zp = ybuf[d ^ 64];
  float rot = (d < 64) ? -zp : zp;
  float o = z * cos_q[l * D + d] + rot * sin_q[l * D + d];
  qbf[(size_t)(head * L + l) * D + d] = f2bf(o);
}

// ---------- KV projection GEMM: BM=64, grid (16,33)=528 blocks (~2/CU) ----------
__launch_bounds__(256)
__global__ void k_kv_gemm(const unsigned short* __restrict__ xc_bf,
                          const unsigned short* __restrict__ wk_bf,
                          const unsigned short* __restrict__ wv_bf,
                          const float* __restrict__ kn_w,
                          const float* __restrict__ cos_k, const float* __restrict__ sin_k,
                          const int* __restrict__ cur_pos, float* __restrict__ cache) {
  const int bn = blockIdx.x;
  const int bm = blockIdx.y;
  const int tid = threadIdx.x, lane = tid & 63, wid = tid >> 6;
  const int wm = wid >> 1, wn = wid & 1;

  __shared__ __align__(16) unsigned char smem[33536];
  unsigned char* A = smem;
  unsigned char* B = smem + 8192;

  const unsigned short* wsrc = (bn < 8) ? wk_bf + (size_t)(bn * 128) * H
                                        : wv_bf + (size_t)((bn - 8) * 128) * H;
  int arow[2], ac8[2], brow[4], bc8[4];
#pragma unroll
  for (int q = 0; q < 2; ++q) {
    int sl = (wid * 2 + q) * 64 + lane;
    int t = bm * 64 + (sl >> 3); if (t > 2063) t = 2063;
    arow[q] = t; ac8[q] = (sl & 7) * 8;
  }
#pragma unroll
  for (int q = 0; q < 4; ++q) {
    int sl = (wid * 4 + q) * 64 + lane;
    brow[q] = sl >> 3; bc8[q] = (sl & 7) * 8;
  }

  f32x4 acc[2][4];
  f32x4 zf = {0.f, 0.f, 0.f, 0.f};
#pragma unroll
  for (int i = 0; i < 2; ++i)
#pragma unroll
    for (int j = 0; j < 4; ++j) acc[i][j] = zf;

  for (int kt = 0; kt < H / 64; ++kt) {
#pragma unroll
    for (int q = 0; q < 2; ++q)
      gl_lds16(xc_bf + (size_t)arow[q] * H + kt * 64 + ac8[q], A + (wid * 2 + q) * 1024);
#pragma unroll
    for (int q = 0; q < 4; ++q)
      gl_lds16(wsrc + (size_t)brow[q] * H + kt * 64 + bc8[q], B + (wid * 4 + q) * 1024);
    __syncthreads();
#pragma unroll
    for (int ks = 0; ks < 2; ++ks) {
      bf16x8 a[2], b[4];
#pragma unroll
      for (int i = 0; i < 2; ++i) {
        int row = wm * 32 + i * 16 + (lane & 15);
        a[i] = *(const bf16x8*)(A + row * 128 + ks * 64 + (lane >> 4) * 16);
      }
#pragma unroll
      for (int j = 0; j < 4; ++j) {
        int nr = wn * 64 + j * 16 + (lane & 15);
        b[j] = *(const bf16x8*)(B + nr * 128 + ks * 64 + (lane >> 4) * 16);
      }
#pragma unroll
      for (int i = 0; i < 2; ++i)
#pragma unroll
        for (int j = 0; j < 4; ++j)
          acc[i][j] = __builtin_amdgcn_mfma_f32_16x16x32_bf16(a[i], b[j], acc[i][j], 0, 0, 0);
    }
    __syncthreads();
  }

  float* cs = (float*)smem;                 // [64][129] f32
  float* lnp = (float*)(smem + 33024);      // [64][2]
  const int pos0 = *cur_pos;
#pragma unroll
  for (int i = 0; i < 2; ++i)
#pragma unroll
    for (int j = 0; j < 4; ++j)
#pragma unroll
      for (int e = 0; e < 4; ++e) {
        int r = wm * 32 + i * 16 + (lane >> 4) * 4 + e;
        int c = wn * 64 + j * 16 + (lane & 15);
        cs[r * 129 + c] = acc[i][j][e];
      }
  __syncthreads();
  if (bn < 8 && tid < 64) {
    int r = tid;
    float sum = 0, sumsq = 0;
    for (int d2 = 0; d2 < 128; ++d2) { float v = cs[r * 129 + d2]; sum += v; sumsq += v * v; }
    float mean = sum * (1.0f / 128.0f);
    float var = sumsq * (1.0f / 128.0f) - mean * mean;
    lnp[r * 2] = mean;
    lnp[r * 2 + 1] = rsqrtf(fmaxf(var, 0.f) + EPS);
  }
  __syncthreads();
  {
    int r = tid >> 2, q = tid & 3;
    int t = bm * 64 + r;
    if (t < T_TOT) {
      if (bn < 8) {
        float mean = lnp[r * 2], rs = lnp[r * 2 + 1];
        float* dst = cache + ((size_t)bn * SL + (size_t)(pos0 + t)) * D;
#pragma unroll
        for (int i8 = 0; i8 < 8; ++i8) {
          int d2 = q * 32 + i8 * 4;
          float4 o4;
          float* o = (float*)&o4;
#pragma unroll
          for (int e = 0; e < 4; ++e) {
            int dd = d2 + e;
            float z = (cs[r * 129 + dd] - mean) * rs * kn_w[dd];
            int p = dd ^ 64;
            float zp = (cs[r * 129 + p] - mean) * rs * kn_w[p];
            float rot = (dd < 64) ? -zp : zp;
            o[e] = z * cos_k[(size_t)t * D + dd] + rot * sin_k[(size_t)t * D + dd];
          }
          *(float4*)(dst + d2) = o4;
        }
      } else {
        float* dst = cache + ((size_t)(NKV + (bn - 8)) * SL + (size_t)(pos0 + t)) * D;
#pragma unroll
        for (int i8 = 0; i8 < 8; ++i8) {
          int d2 = q * 32 + i8 * 4;
          float4 o4 = { cs[r * 129 + d2], cs[r * 129 + d2 + 1], cs[r * 129 + d2 + 2], cs[r * 129 + d2 + 3] };
          *(float4*)(dst + d2) = o4;
        }
      }
    }
  }
}

// ---------- fused flash attention + cache pass-through (mask via Mlds float4) ----------
__launch_bounds__(256)
__global__ void k_attn(const float* __restrict__ kv_src, float* __restrict__ cache,
                       const unsigned short* __restrict__ qbf, const float* __restrict__ mask,
                       const int* __restrict__ cur_pos,
                       unsigned short* __restrict__ part_O,
                       float* __restrict__ part_m, float* __restrict__ part_l) {
  const int g = blockIdx.x;   // kv head
  const int ch = blockIdx.y;  // 0..95
  const int tid = threadIdx.x, lane = tid & 63, w = tid >> 6;
  const int t0 = ch * 5 + (ch < 32 ? ch : 32);
  const int t1 = t0 + 5 + (ch < 32 ? 1 : 0);
  const int pos0 = *cur_pos, pos1 = pos0 + T_TOT;

  __shared__ __align__(16) unsigned short Klds[64 * 136];   // 17408 B
  __shared__ __align__(16) unsigned short Vt[128 * 72];     // 18432 B
  __shared__ __align__(16) unsigned short Plds[4 * 16 * 72];// 9216 B
  __shared__ __align__(16) float Mlds[16 * 68];             // 4352 B

  bf16x8 qf[4];
#pragma unroll
  for (int ks = 0; ks < 4; ++ks)
    qf[ks] = *(const bf16x8*)(qbf + ((size_t)(g * 4 + w) * L + (lane & 15)) * D + ks * 32 + (lane >> 4) * 8);

  f32x4 O[8];
  f32x4 zf = {0.f, 0.f, 0.f, 0.f};
#pragma unroll
  for (int j = 0; j < 8; ++j) O[j] = zf;
  float mrow[4] = {-1e30f, -1e30f, -1e30f, -1e30f};
  float lrow[4] = {0, 0, 0, 0};
  unsigned short* Pw = Plds + w * 16 * 72;

  float4 ka[4], kb[4], va[4], vb[4], mr;
  int pp[4];

#define LOADT(ti_) do {                                                         \
    _Pragma("unroll")                                                           \
    for (int g2 = 0; g2 < 4; ++g2) {                                            \
      int slot = tid + g2 * 256;                                                \
      int pos = slot >> 4, c0 = (slot & 15) * 8;                                \
      int p = (ti_) * 64 + pos;                                                 \
      pp[g2] = p;                                                               \
      bool u = (p >= pos0) & (p < pos1);                                        \
      const float* sp = u ? cache : kv_src;                                     \
      size_t kidx = ((size_t)g * SL + p) * D + c0;                              \
      size_t vidx = ((size_t)(NKV + g) * SL + p) * D + c0;                      \
      ka[g2] = *(const float4*)(sp + kidx);                                     \
      kb[g2] = *(const float4*)(sp + kidx + 4);                                 \
      va[g2] = *(const float4*)(sp + vidx);                                     \
      vb[g2] = *(const float4*)(sp + vidx + 4);                                 \
    }                                                                           \
    mr = *(const float4*)(mask + (size_t)(tid >> 4) * SL + (ti_) * 64 + (tid & 15) * 4); \
  } while (0)

#define WRITET() do {                                                           \
    _Pragma("unroll")                                                           \
    for (int g2 = 0; g2 < 4; ++g2) {                                            \
      int slot = tid + g2 * 256;                                                \
      int pos = slot >> 4, c0 = (slot & 15) * 8;                                \
      int p = pp[g2];                                                           \
      bool u = (p >= pos0) & (p < pos1);                                        \
      if (!u) {                                                                 \
        size_t kidx = ((size_t)g * SL + p) * D + c0;                            \
        size_t vidx = ((size_t)(NKV + g) * SL + p) * D + c0;                    \
        *(float4*)(cache + kidx) = ka[g2];                                      \
        *(float4*)(cache + kidx + 4) = kb[g2];                                  \
        *(float4*)(cache + vidx) = va[g2];                                      \
        *(float4*)(cache + vidx + 4) = vb[g2];                                  \
      }                                                                         \
      float kf[8] = {ka[g2].x, ka[g2].y, ka[g2].z, ka[g2].w,                    \
                     kb[g2].x, kb[g2].y, kb[g2].z, kb[g2].w};                   \
      st8lds(Klds + pos * 136 + c0, kf);                                        \
      float vf[8] = {va[g2].x, va[g2].y, va[g2].z, va[g2].w,                    \
                     vb[g2].x, vb[g2].y, vb[g2].z, vb[g2].w};                   \
      _Pragma("unroll")                                                         \
      for (int jj = 0; jj < 8; ++jj) {                                          \
        int dd = c0 + jj;                                                       \
        Vt[dd * 72 + (pos ^ (((dd >> 3) & 7) << 3))] = f2bf(vf[jj]);            \
      }                                                                         \
    }                                                                           \
    *(float4*)(&Mlds[(tid >> 4) * 68 + (tid & 15) * 4]) = mr;                   \
  } while (0)

  LOADT(t0);
  for (int ti = t0; ti < t1; ++ti) {
    WRITET();
    if (ti + 1 < t1) LOADT(ti + 1);
    __syncthreads();

    // ---- QK^T ----
    f32x4 Sv[4];
#pragma unroll
    for (int nf = 0; nf < 4; ++nf) {
      f32x4 accs = zf;
#pragma unroll
      for (int ks = 0; ks < 4; ++ks) {
        int pl = nf * 16 + (lane & 15);
        bf16x8 bk = *(const bf16x8*)(Klds + pl * 136 + ks * 32 + (lane >> 4) * 8);
        accs = __builtin_amdgcn_mfma_f32_16x16x32_bf16(qf[ks], bk, accs, 0, 0, 0);
      }
      Sv[nf] = accs;
    }

    // ---- online softmax (mask from Mlds) ----
#pragma unroll
    for (int e = 0; e < 4; ++e) {
      int lq = (lane >> 4) * 4 + e;
      float sc[4];
#pragma unroll
      for (int nf = 0; nf < 4; ++nf)
        sc[nf] = Sv[nf][e] * SCALE + Mlds[lq * 68 + nf * 16 + (lane & 15)];
      float tmax = fmaxf(fmaxf(sc[0], sc[1]), fmaxf(sc[2], sc[3]));
#pragma unroll
      for (int mm = 1; mm < 16; mm <<= 1) tmax = fmaxf(tmax, __shfl_xor(tmax, mm));
      float mnew = fmaxf(mrow[e], tmax);
      float alpha = __expf(mrow[e] - mnew);
      float psum = 0;
#pragma unroll
      for (int nf = 0; nf < 4; ++nf) {
        float p = __expf(sc[nf] - mnew);
        psum += p;
        Pw[lq * 72 + nf * 16 + (lane & 15)] = f2bf(p);
      }
#pragma unroll
      for (int mm = 1; mm < 16; mm <<= 1) psum += __shfl_xor(psum, mm);
      lrow[e] = lrow[e] * alpha + psum;
      mrow[e] = mnew;
#pragma unroll
      for (int j = 0; j < 8; ++j) O[j][e] *= alpha;
    }

    // ---- PV ----
#pragma unroll
    for (int ks2 = 0; ks2 < 2; ++ks2) {
      bf16x8 ap = *(const bf16x8*)(Pw + (lane & 15) * 72 + ks2 * 32 + (lane >> 4) * 8);
#pragma unroll
      for (int jf = 0; jf < 8; ++jf) {
        int dd = jf * 16 + (lane & 15);
        int po = (ks2 * 32 + (lane >> 4) * 8) ^ (((dd >> 3) & 7) << 3);
        bf16x8 bv = *(const bf16x8*)(Vt + dd * 72 + po);
        O[jf] = __builtin_amdgcn_mfma_f32_16x16x32_bf16(ap, bv, O[jf], 0, 0, 0);
      }
    }
    __syncthreads();
  }
#undef LOADT
#undef WRITET

  const int cidx = g * NCHUNK + ch;
#pragma unroll
  for (int jf = 0; jf < 8; ++jf)
#pragma unroll
    for (int e = 0; e < 4; ++e) {
      int qr = w * 16 + (lane >> 4) * 4 + e;
      part_O[((size_t)cidx * 64 + qr) * D + jf * 16 + (lane & 15)] = f2bf(O[jf][e]);
    }
  if ((lane & 15) == 0) {
#pragma unroll
    for (int e = 0; e < 4; ++e) {
      int qr = w * 16 + (lane >> 4) * 4 + e;
      part_m[cidx * 64 + qr] = mrow[e];
      part_l[cidx * 64 + qr] = lrow[e];
    }
  }
}

// ---------- combine partials ----------
__global__ void k_attn_reduce(const unsigned short* __restrict__ part_O,
                              const float* __restrict__ part_m,
                              const float* __restrict__ part_l,
                              unsigned short* __restrict__ attnbf) {
  const int g = blockIdx.x >> 6;
  const int qr = blockIdx.x & 63;
  const int d = threadIdx.x;
  float M = -1e30f;
  for (int c = 0; c < NCHUNK; ++c) M = fmaxf(M, part_m[(g * NCHUNK + c) * 64 + qr]);
  float Lsum = 0, acc = 0;
  for (int c = 0; c < NCHUNK; ++c) {
    float wgt = __expf(part_m[(g * NCHUNK + c) * 64 + qr] - M);
    Lsum += part_l[(g * NCHUNK + c) * 64 + qr] * wgt;
    acc += wgt * bf2f(part_O[((size_t)(g * NCHUNK + c) * 64 + qr) * D + d]);
  }
  float o = acc / fmaxf(Lsum, 1e-20f);
  int h = g * 4 + (qr >> 4), l = qr & 15;
  attnbf[(size_t)l * 4096 + h * 128 + d] = f2bf(o);
}

// ---------- output projection: wo read f32 directly, reg-staged ----------
__launch_bounds__(256)
__global__ void k_out_gemm(const unsigned short* __restrict__ attnbf,
                           const float* __restrict__ wo,
                           float* __restrict__ part_out) {
  const int ntile = blockIdx.x;
  const int ksp = blockIdx.y;
  const int tid = threadIdx.x, lane = tid & 63, w = tid >> 6;
  __shared__ __align__(16) unsigned char Asm[2048];
  __shared__ __align__(16) unsigned char Bsm[16384];

  f32x4 zf = {0.f, 0.f, 0.f, 0.f};
  f32x4 acc[2] = {zf, zf};
  for (int it = 0; it < 4; ++it) {
    if (w < 2) {
      int sl = w * 64 + lane;
      gl_lds16(attnbf + (size_t)(sl >> 3) * 4096 + ksp * 256 + it * 64 + (sl & 7) * 8, Asm + w * 1024);
    }
#pragma unroll
    for (int q = 0; q < 4; ++q) {
      int sl = (w * 4 + q) * 64 + lane;
      int row = sl >> 3, c0 = (sl & 7) * 8;
      float v8[8];
      ld8f(wo + (size_t)(ntile * 128 + row) * 4096 + ksp * 256 + it * 64 + c0, v8);
      st8lds((unsigned short*)Bsm + row * 64 + c0, v8);
    }
    __syncthreads();
#pragma unroll
    for (int ks = 0; ks < 2; ++ks) {
      bf16x8 a = *(const bf16x8*)(Asm + (lane & 15) * 128 + ks * 64 + (lane >> 4) * 16);
#pragma unroll
      for (int j = 0; j < 2; ++j) {
        int nr = w * 32 + j * 16 + (lane & 15);
        bf16x8 b = *(const bf16x8*)(Bsm + nr * 128 + ks * 64 + (lane >> 4) * 16);
        acc[j] = __builtin_amdgcn_mfma_f32_16x16x32_bf16(a, b, acc[j], 0, 0, 0);
      }
    }
    __syncthreads();
  }
#pragma unroll
  for (int j = 0; j < 2; ++j)
#pragma unroll
    for (int e = 0; e < 4; ++e) {
      int lq = (lane >> 4) * 4 + e;
      int n = ntile * 128 + w * 32 + j * 16 + (lane & 15);
      part_out[(size_t)ksp * 32768 + lq * 2048 + n] = acc[j][e];
    }
}

__global__ void k_out_combine(const float* __restrict__ part_out, float* __restrict__ out0) {
  int i = blockIdx.x * 256 + threadIdx.x;
  if (i < 32768) {
    float v = 0;
    for (int c = 0; c < 16; ++c) v += part_out[c * 32768 + i];
    out0[i] = v;
  }
}

extern "C" void kernel_launch(void* const* d_in, const int* in_sizes, int n_in,
                              void* d_out, int out_size, void* d_ws, size_t ws_size,
                              hipStream_t stream) {
  const float* x     = (const float*)d_in[0];
  const float* x_ctx = (const float*)d_in[1];
  const float* cos_q = (const float*)d_in[2];
  const float* sin_q = (const float*)d_in[3];
  const float* cos_k = (const float*)d_in[4];
  const float* sin_k = (const float*)d_in[5];
  const float* kv    = (const float*)d_in[6];
  const float* mask  = (const float*)d_in[7];
  const float* wq    = (const float*)d_in[8];
  const float* wk    = (const float*)d_in[9];
  const float* wv    = (const float*)d_in[10];
  const float* wo    = (const float*)d_in[11];
  const float* qn_w  = (const float*)d_in[12];
  const float* kn_w  = (const float*)d_in[13];
  const int* cur_pos = (const int*)d_in[14];

  float* out0 = (float*)d_out;
  float* cache = out0 + 32768;

  uint8_t* ws = (uint8_t*)d_ws;
  unsigned short* xc_bf  = (unsigned short*)(ws);               // 0x810000
  unsigned short* wk_bf  = (unsigned short*)(ws + 0x0810000);   // 0x400000
  unsigned short* wv_bf  = (unsigned short*)(ws + 0x0C10000);   // 0x400000
  float* qpart           = (float*)(ws + 0x1010000);            // 0x400000
  unsigned short* qbf    = (unsigned short*)(ws + 0x1410000);   // 0x20000
  unsigned short* attnbf = (unsigned short*)(ws + 0x1430000);   // 0x20000
  unsigned short* part_O = (unsigned short*)(ws + 0x1450000);   // 0xC00000
  float* part_m          = (float*)(ws + 0x2050000);            // 0x30000
  float* part_l          = (float*)(ws + 0x2090000);            // 0x30000
  float* part_out        = (float*)(ws + 0x20D0000);            // 0x200000

  unsigned short* xq_bf = xc_bf + (size_t)2048 * H;

  k_conv<<<dim3(4112), dim3(256), 0, stream>>>(wk, wv, x_ctx, x, wk_bf, wv_bf, xc_bf);
  k_q_proj<<<dim3(32, 16), dim3(256), 0, stream>>>(xq_bf, wq, qpart);
  k_q_fin<<<dim3(512), dim3(128), 0, stream>>>(qpart, qn_w, cos_q, sin_q, qbf);
  k_kv_gemm<<<dim3(16, 33), dim3(256), 0, stream>>>(xc_bf, wk_bf, wv_bf, kn_w, cos_k, sin_k, cur_pos, cache);
  k_attn<<<dim3(8, NCHUNK), dim3(256), 0, stream>>>(kv, cache, qbf, mask, cur_pos, part_O, part_m, part_l);
  k_attn_reduce<<<dim3(512), dim3(128), 0, stream>>>(part_O, part_m, part_l, attnbf);
  k_out_gemm<<<dim3(16, 16), dim3(256), 0, stream>>>(attnbf, wo, part_out);
  k_out_combine<<<dim3(128), dim3(256), 0, stream>>>(part_out, out0);
}

// Round 12
// 218.832 us; speedup vs baseline: 1.1882x; 1.1882x over previous
//
#include <hip/hip_runtime.h>
#include <hip/hip_bf16.h>
#include <stdint.h>

#define H 2048
#define L 16
#define D 128
#define NH 32
#define NKV 8
#define SL 32768
#define T_TOT 2064
#define EPS 1e-6f
#define SCALE 0.08838834764831845f
#define NCHUNK 96

typedef __bf16 bf16x8 __attribute__((ext_vector_type(8)));
typedef float f32x4 __attribute__((ext_vector_type(4)));

__device__ __forceinline__ float bf2f(unsigned short u) {
  union { uint32_t i; float f; } v; v.i = ((uint32_t)u) << 16; return v.f;
}
__device__ __forceinline__ unsigned short f2bf(float f) {
  union { float f; uint32_t i; } v; v.f = f;
  uint32_t u = v.i;
  return (unsigned short)((u + 0x7FFFu + ((u >> 16) & 1u)) >> 16);
}
__device__ __forceinline__ void ld8f(const float* p, float* o) {
  float4 a = *(const float4*)p;
  float4 b = *(const float4*)(p + 4);
  o[0]=a.x; o[1]=a.y; o[2]=a.z; o[3]=a.w;
  o[4]=b.x; o[5]=b.y; o[6]=b.z; o[7]=b.w;
}
__device__ __forceinline__ void st8lds(unsigned short* d, const float* v) {
  unsigned short t[8];
#pragma unroll
  for (int j = 0; j < 8; ++j) t[j] = f2bf(v[j]);
  *(uint4*)d = *(const uint4*)t;
}
__device__ __forceinline__ void gl_lds16(const void* g, void* l) {
  __builtin_amdgcn_global_load_lds(
      (const __attribute__((address_space(1))) void*)g,
      (__attribute__((address_space(3))) void*)l, 16, 0, 0);
}

// ---------- f32 -> bf16 conversion (only multi-read tensors: wk, wv, x_ctx, x) ----------
__global__ void k_conv(const float* __restrict__ wk, const float* __restrict__ wv,
                       const float* __restrict__ x_ctx, const float* __restrict__ x,
                       unsigned short* __restrict__ wk_bf, unsigned short* __restrict__ wv_bf,
                       unsigned short* __restrict__ xc_bf) {
  size_t li = (size_t)blockIdx.x * 256 + threadIdx.x;
  const float* src; unsigned short* dst;
  if (li < 262144) { src = wk; dst = wk_bf; }
  else if ((li -= 262144) < 262144) { src = wv; dst = wv_bf; }
  else if ((li -= 262144) < 524288) { src = x_ctx; dst = xc_bf; }
  else if ((li -= 524288) < 4096) { src = x; dst = xc_bf + (size_t)2048 * H; }
  else return;
  float v8[8];
  ld8f(src + li * 8, v8);
  unsigned short t[8];
#pragma unroll
  for (int j = 0; j < 8; ++j) t[j] = f2bf(v8[j]);
  *(uint4*)(dst + li * 8) = *(const uint4*)t;
}

// ---------- Q projection: wq read f32 directly (use-once), reg-staged to bf16 LDS ----------
__launch_bounds__(256)
__global__ void k_q_proj(const unsigned short* __restrict__ xq_bf,
                         const float* __restrict__ wq,
                         float* __restrict__ qpart) {
  const int h = blockIdx.x, s = blockIdx.y;
  const int tid = threadIdx.x, lane = tid & 63, w = tid >> 6;
  __shared__ __align__(16) unsigned char Asm[2048];
  __shared__ __align__(16) unsigned char Bsm[16384];
  f32x4 zf = {0.f, 0.f, 0.f, 0.f};
  f32x4 acc[2] = {zf, zf};
  for (int kt = 0; kt < 2; ++kt) {
    if (w < 2) {
      int sl = w * 64 + lane;
      gl_lds16(xq_bf + (size_t)(sl >> 3) * H + s * 128 + kt * 64 + (sl & 7) * 8, Asm + w * 1024);
    }
#pragma unroll
    for (int q = 0; q < 4; ++q) {
      int sl = (w * 4 + q) * 64 + lane;
      int row = sl >> 3, c0 = (sl & 7) * 8;
      float v8[8];
      ld8f(wq + (size_t)(h * 128 + row) * H + s * 128 + kt * 64 + c0, v8);
      st8lds((unsigned short*)Bsm + row * 64 + c0, v8);
    }
    __syncthreads();
#pragma unroll
    for (int ks = 0; ks < 2; ++ks) {
      bf16x8 a = *(const bf16x8*)(Asm + (lane & 15) * 128 + ks * 64 + (lane >> 4) * 16);
#pragma unroll
      for (int j = 0; j < 2; ++j) {
        int nr = w * 32 + j * 16 + (lane & 15);
        bf16x8 b = *(const bf16x8*)(Bsm + nr * 128 + ks * 64 + (lane >> 4) * 16);
        acc[j] = __builtin_amdgcn_mfma_f32_16x16x32_bf16(a, b, acc[j], 0, 0, 0);
      }
    }
    __syncthreads();
  }
#pragma unroll
  for (int j = 0; j < 2; ++j)
#pragma unroll
    for (int e = 0; e < 4; ++e) {
      int lq = (lane >> 4) * 4 + e;
      int col = w * 32 + j * 16 + (lane & 15);
      qpart[((size_t)(s * NH + h) * L + lq) * D + col] = acc[j][e];
    }
}

// ---------- Q finalize ----------
__global__ void k_q_fin(const float* __restrict__ qpart, const float* __restrict__ qn_w,
                        const float* __restrict__ cos_q, const float* __restrict__ sin_q,
                        unsigned short* __restrict__ qbf) {
  const int head = blockIdx.x >> 4;
  const int l = blockIdx.x & 15;
  const int d = threadIdx.x;
  __shared__ float ybuf[128];
  __shared__ float red[4];
  float v = 0;
  for (int s = 0; s < 16; ++s) v += qpart[((size_t)(s * NH + head) * L + l) * D + d];
  float s1 = v, s2 = v * v;
  for (int m = 1; m < 64; m <<= 1) { s1 += __shfl_xor(s1, m); s2 += __shfl_xor(s2, m); }
  if ((threadIdx.x & 63) == 0) { red[(threadIdx.x >> 6) * 2] = s1; red[(threadIdx.x >> 6) * 2 + 1] = s2; }
  __syncthreads();
  float sum = red[0] + red[2], sumsq = red[1] + red[3];
  float mean = sum * (1.0f / 128.0f);
  float var = sumsq * (1.0f / 128.0f) - mean * mean;
  float rs = rsqrtf(fmaxf(var, 0.f) + EPS);
  float z = (v - mean) * rs * qn_w[d];
  ybuf[d] = z;
  __syncthreads();
  float zp = ybuf[d ^ 64];
  float rot = (d < 64) ? -zp : zp;
  float o = z * cos_q[l * D + d] + rot * sin_q[l * D + d];
  qbf[(size_t)(head * L + l) * D + d] = f2bf(o);
}

// ---------- KV projection GEMM: BM=64, grid (16,33)=528 blocks (~2/CU) ----------
__launch_bounds__(256)
__global__ void k_kv_gemm(const unsigned short* __restrict__ xc_bf,
                          const unsigned short* __restrict__ wk_bf,
                          const unsigned short* __restrict__ wv_bf,
                          const float* __restrict__ kn_w,
                          const float* __restrict__ cos_k, const float* __restrict__ sin_k,
                          const int* __restrict__ cur_pos, float* __restrict__ cache) {
  const int bn = blockIdx.x;
  const int bm = blockIdx.y;
  const int tid = threadIdx.x, lane = tid & 63, wid = tid >> 6;
  const int wm = wid >> 1, wn = wid & 1;

  __shared__ __align__(16) unsigned char smem[33536];
  unsigned char* A = smem;
  unsigned char* B = smem + 8192;

  const unsigned short* wsrc = (bn < 8) ? wk_bf + (size_t)(bn * 128) * H
                                        : wv_bf + (size_t)((bn - 8) * 128) * H;
  int arow[2], ac8[2], brow[4], bc8[4];
#pragma unroll
  for (int q = 0; q < 2; ++q) {
    int sl = (wid * 2 + q) * 64 + lane;
    int t = bm * 64 + (sl >> 3); if (t > 2063) t = 2063;
    arow[q] = t; ac8[q] = (sl & 7) * 8;
  }
#pragma unroll
  for (int q = 0; q < 4; ++q) {
    int sl = (wid * 4 + q) * 64 + lane;
    brow[q] = sl >> 3; bc8[q] = (sl & 7) * 8;
  }

  f32x4 acc[2][4];
  f32x4 zf = {0.f, 0.f, 0.f, 0.f};
#pragma unroll
  for (int i = 0; i < 2; ++i)
#pragma unroll
    for (int j = 0; j < 4; ++j) acc[i][j] = zf;

  for (int kt = 0; kt < H / 64; ++kt) {
#pragma unroll
    for (int q = 0; q < 2; ++q)
      gl_lds16(xc_bf + (size_t)arow[q] * H + kt * 64 + ac8[q], A + (wid * 2 + q) * 1024);
#pragma unroll
    for (int q = 0; q < 4; ++q)
      gl_lds16(wsrc + (size_t)brow[q] * H + kt * 64 + bc8[q], B + (wid * 4 + q) * 1024);
    __syncthreads();
#pragma unroll
    for (int ks = 0; ks < 2; ++ks) {
      bf16x8 a[2], b[4];
#pragma unroll
      for (int i = 0; i < 2; ++i) {
        int row = wm * 32 + i * 16 + (lane & 15);
        a[i] = *(const bf16x8*)(A + row * 128 + ks * 64 + (lane >> 4) * 16);
      }
#pragma unroll
      for (int j = 0; j < 4; ++j) {
        int nr = wn * 64 + j * 16 + (lane & 15);
        b[j] = *(const bf16x8*)(B + nr * 128 + ks * 64 + (lane >> 4) * 16);
      }
#pragma unroll
      for (int i = 0; i < 2; ++i)
#pragma unroll
        for (int j = 0; j < 4; ++j)
          acc[i][j] = __builtin_amdgcn_mfma_f32_16x16x32_bf16(a[i], b[j], acc[i][j], 0, 0, 0);
    }
    __syncthreads();
  }

  float* cs = (float*)smem;                 // [64][129] f32
  float* lnp = (float*)(smem + 33024);      // [64][2]
  const int pos0 = *cur_pos;
#pragma unroll
  for (int i = 0; i < 2; ++i)
#pragma unroll
    for (int j = 0; j < 4; ++j)
#pragma unroll
      for (int e = 0; e < 4; ++e) {
        int r = wm * 32 + i * 16 + (lane >> 4) * 4 + e;
        int c = wn * 64 + j * 16 + (lane & 15);
        cs[r * 129 + c] = acc[i][j][e];
      }
  __syncthreads();
  if (bn < 8 && tid < 64) {
    int r = tid;
    float sum = 0, sumsq = 0;
    for (int d2 = 0; d2 < 128; ++d2) { float v = cs[r * 129 + d2]; sum += v; sumsq += v * v; }
    float mean = sum * (1.0f / 128.0f);
    float var = sumsq * (1.0f / 128.0f) - mean * mean;
    lnp[r * 2] = mean;
    lnp[r * 2 + 1] = rsqrtf(fmaxf(var, 0.f) + EPS);
  }
  __syncthreads();
  {
    int r = tid >> 2, q = tid & 3;
    int t = bm * 64 + r;
    if (t < T_TOT) {
      if (bn < 8) {
        float mean = lnp[r * 2], rs = lnp[r * 2 + 1];
        float* dst = cache + ((size_t)bn * SL + (size_t)(pos0 + t)) * D;
#pragma unroll
        for (int i8 = 0; i8 < 8; ++i8) {
          int d2 = q * 32 + i8 * 4;
          float4 o4;
          float* o = (float*)&o4;
#pragma unroll
          for (int e = 0; e < 4; ++e) {
            int dd = d2 + e;
            float z = (cs[r * 129 + dd] - mean) * rs * kn_w[dd];
            int p = dd ^ 64;
            float zp = (cs[r * 129 + p] - mean) * rs * kn_w[p];
            float rot = (dd < 64) ? -zp : zp;
            o[e] = z * cos_k[(size_t)t * D + dd] + rot * sin_k[(size_t)t * D + dd];
          }
          *(float4*)(dst + d2) = o4;
        }
      } else {
        float* dst = cache + ((size_t)(NKV + (bn - 8)) * SL + (size_t)(pos0 + t)) * D;
#pragma unroll
        for (int i8 = 0; i8 < 8; ++i8) {
          int d2 = q * 32 + i8 * 4;
          float4 o4 = { cs[r * 129 + d2], cs[r * 129 + d2 + 1], cs[r * 129 + d2 + 2], cs[r * 129 + d2 + 3] };
          *(float4*)(dst + d2) = o4;
        }
      }
    }
  }
}

// ---------- fused flash attention + cache pass-through (round-10 form: reg mask) ----------
__launch_bounds__(256)
__global__ void k_attn(const float* __restrict__ kv_src, float* __restrict__ cache,
                       const unsigned short* __restrict__ qbf, const float* __restrict__ mask,
                       const int* __restrict__ cur_pos,
                       unsigned short* __restrict__ part_O,
                       float* __restrict__ part_m, float* __restrict__ part_l) {
  const int g = blockIdx.x;   // kv head
  const int ch = blockIdx.y;  // 0..95
  const int tid = threadIdx.x, lane = tid & 63, w = tid >> 6;
  const int t0 = ch * 5 + (ch < 32 ? ch : 32);
  const int t1 = t0 + 5 + (ch < 32 ? 1 : 0);
  const int pos0 = *cur_pos, pos1 = pos0 + T_TOT;

  __shared__ __align__(16) unsigned short Klds[64 * 136];
  __shared__ __align__(16) unsigned short Vt[128 * 72];
  __shared__ __align__(16) unsigned short Plds[4 * 16 * 72];

  bf16x8 qf[4];
#pragma unroll
  for (int ks = 0; ks < 4; ++ks)
    qf[ks] = *(const bf16x8*)(qbf + ((size_t)(g * 4 + w) * L + (lane & 15)) * D + ks * 32 + (lane >> 4) * 8);

  f32x4 O[8];
  f32x4 zf = {0.f, 0.f, 0.f, 0.f};
#pragma unroll
  for (int j = 0; j < 8; ++j) O[j] = zf;
  float mrow[4] = {-1e30f, -1e30f, -1e30f, -1e30f};
  float lrow[4] = {0, 0, 0, 0};
  unsigned short* Pw = Plds + w * 16 * 72;

  float4 ka[4], kb[4], va[4], vb[4];
  float mrgC[16], mrgN[16];
  int pp[4];

#define LOADT(ti_) do {                                                         \
    _Pragma("unroll")                                                           \
    for (int g2 = 0; g2 < 4; ++g2) {                                            \
      int slot = tid + g2 * 256;                                                \
      int pos = slot >> 4, c0 = (slot & 15) * 8;                                \
      int p = (ti_) * 64 + pos;                                                 \
      pp[g2] = p;                                                               \
      bool u = (p >= pos0) & (p < pos1);                                        \
      const float* sp = u ? cache : kv_src;                                     \
      size_t kidx = ((size_t)g * SL + p) * D + c0;                              \
      size_t vidx = ((size_t)(NKV + g) * SL + p) * D + c0;                      \
      ka[g2] = *(const float4*)(sp + kidx);                                     \
      kb[g2] = *(const float4*)(sp + kidx + 4);                                 \
      va[g2] = *(const float4*)(sp + vidx);                                     \
      vb[g2] = *(const float4*)(sp + vidx + 4);                                 \
    }                                                                           \
    _Pragma("unroll")                                                           \
    for (int ee = 0; ee < 4; ++ee)                                              \
      _Pragma("unroll")                                                         \
      for (int nf2 = 0; nf2 < 4; ++nf2)                                         \
        mrgN[ee * 4 + nf2] = mask[(size_t)((lane >> 4) * 4 + ee) * SL +         \
                                  (ti_) * 64 + nf2 * 16 + (lane & 15)];         \
  } while (0)

#define WRITET() do {                                                           \
    _Pragma("unroll")                                                           \
    for (int g2 = 0; g2 < 4; ++g2) {                                            \
      int slot = tid + g2 * 256;                                                \
      int pos = slot >> 4, c0 = (slot & 15) * 8;                                \
      int p = pp[g2];                                                           \
      bool u = (p >= pos0) & (p < pos1);                                        \
      if (!u) {                                                                 \
        size_t kidx = ((size_t)g * SL + p) * D + c0;                            \
        size_t vidx = ((size_t)(NKV + g) * SL + p) * D + c0;                    \
        *(float4*)(cache + kidx) = ka[g2];                                      \
        *(float4*)(cache + kidx + 4) = kb[g2];                                  \
        *(float4*)(cache + vidx) = va[g2];                                      \
        *(float4*)(cache + vidx + 4) = vb[g2];                                  \
      }                                                                         \
      float kf[8] = {ka[g2].x, ka[g2].y, ka[g2].z, ka[g2].w,                    \
                     kb[g2].x, kb[g2].y, kb[g2].z, kb[g2].w};                   \
      st8lds(Klds + pos * 136 + c0, kf);                                        \
      float vf[8] = {va[g2].x, va[g2].y, va[g2].z, va[g2].w,                    \
                     vb[g2].x, vb[g2].y, vb[g2].z, vb[g2].w};                   \
      _Pragma("unroll")                                                         \
      for (int jj = 0; jj < 8; ++jj) {                                          \
        int dd = c0 + jj;                                                       \
        Vt[dd * 72 + (pos ^ (((dd >> 3) & 7) << 3))] = f2bf(vf[jj]);            \
      }                                                                         \
    }                                                                           \
  } while (0)

  LOADT(t0);
  for (int ti = t0; ti < t1; ++ti) {
    WRITET();
#pragma unroll
    for (int ii = 0; ii < 16; ++ii) mrgC[ii] = mrgN[ii];
    if (ti + 1 < t1) LOADT(ti + 1);
    __syncthreads();

    // ---- QK^T ----
    f32x4 Sv[4];
#pragma unroll
    for (int nf = 0; nf < 4; ++nf) {
      f32x4 accs = zf;
#pragma unroll
      for (int ks = 0; ks < 4; ++ks) {
        int pl = nf * 16 + (lane & 15);
        bf16x8 bk = *(const bf16x8*)(Klds + pl * 136 + ks * 32 + (lane >> 4) * 8);
        accs = __builtin_amdgcn_mfma_f32_16x16x32_bf16(qf[ks], bk, accs, 0, 0, 0);
      }
      Sv[nf] = accs;
    }

    // ---- online softmax ----
#pragma unroll
    for (int e = 0; e < 4; ++e) {
      int lq = (lane >> 4) * 4 + e;
      float sc[4];
#pragma unroll
      for (int nf = 0; nf < 4; ++nf)
        sc[nf] = Sv[nf][e] * SCALE + mrgC[e * 4 + nf];
      float tmax = fmaxf(fmaxf(sc[0], sc[1]), fmaxf(sc[2], sc[3]));
#pragma unroll
      for (int mm = 1; mm < 16; mm <<= 1) tmax = fmaxf(tmax, __shfl_xor(tmax, mm));
      float mnew = fmaxf(mrow[e], tmax);
      float alpha = __expf(mrow[e] - mnew);
      float psum = 0;
#pragma unroll
      for (int nf = 0; nf < 4; ++nf) {
        float p = __expf(sc[nf] - mnew);
        psum += p;
        Pw[lq * 72 + nf * 16 + (lane & 15)] = f2bf(p);
      }
#pragma unroll
      for (int mm = 1; mm < 16; mm <<= 1) psum += __shfl_xor(psum, mm);
      lrow[e] = lrow[e] * alpha + psum;
      mrow[e] = mnew;
#pragma unroll
      for (int j = 0; j < 8; ++j) O[j][e] *= alpha;
    }

    // ---- PV ----
#pragma unroll
    for (int ks2 = 0; ks2 < 2; ++ks2) {
      bf16x8 ap = *(const bf16x8*)(Pw + (lane & 15) * 72 + ks2 * 32 + (lane >> 4) * 8);
#pragma unroll
      for (int jf = 0; jf < 8; ++jf) {
        int dd = jf * 16 + (lane & 15);
        int po = (ks2 * 32 + (lane >> 4) * 8) ^ (((dd >> 3) & 7) << 3);
        bf16x8 bv = *(const bf16x8*)(Vt + dd * 72 + po);
        O[jf] = __builtin_amdgcn_mfma_f32_16x16x32_bf16(ap, bv, O[jf], 0, 0, 0);
      }
    }
    __syncthreads();
  }
#undef LOADT
#undef WRITET

  const int cidx = g * NCHUNK + ch;
#pragma unroll
  for (int jf = 0; jf < 8; ++jf)
#pragma unroll
    for (int e = 0; e < 4; ++e) {
      int qr = w * 16 + (lane >> 4) * 4 + e;
      part_O[((size_t)cidx * 64 + qr) * D + jf * 16 + (lane & 15)] = f2bf(O[jf][e]);
    }
  if ((lane & 15) == 0) {
#pragma unroll
    for (int e = 0; e < 4; ++e) {
      int qr = w * 16 + (lane >> 4) * 4 + e;
      part_m[cidx * 64 + qr] = mrow[e];
      part_l[cidx * 64 + qr] = lrow[e];
    }
  }
}

// ---------- combine partials (block-cooperative M/Lsum, weights cached in LDS) ----------
__global__ void k_attn_reduce(const unsigned short* __restrict__ part_O,
                              const float* __restrict__ part_m,
                              const float* __restrict__ part_l,
                              unsigned short* __restrict__ attnbf) {
  const int g = blockIdx.x >> 6;
  const int qr = blockIdx.x & 63;
  const int d = threadIdx.x;  // 128 threads
  __shared__ float Wlds[NCHUNK];
  __shared__ float rmax[2];
  __shared__ float rsum[2];

  // threads 0..95 load the per-chunk m values (coalesced across blocks via L2)
  float mv = (d < NCHUNK) ? part_m[(g * NCHUNK + d) * 64 + qr] : -1e30f;
  float t = mv;
  for (int mm = 1; mm < 64; mm <<= 1) t = fmaxf(t, __shfl_xor(t, mm));
  if ((d & 63) == 0) rmax[d >> 6] = t;
  __syncthreads();
  float M = fmaxf(rmax[0], rmax[1]);

  float wgt = (d < NCHUNK) ? __expf(mv - M) : 0.f;
  float lv = (d < NCHUNK) ? part_l[(g * NCHUNK + d) * 64 + qr] * wgt : 0.f;
  if (d < NCHUNK) Wlds[d] = wgt;
  float s = lv;
  for (int mm = 1; mm < 64; mm <<= 1) s += __shfl_xor(s, mm);
  if ((d & 63) == 0) rsum[d >> 6] = s;
  __syncthreads();
  float Lsum = rsum[0] + rsum[1];

  float acc = 0;
  for (int c = 0; c < NCHUNK; ++c)
    acc += Wlds[c] * bf2f(part_O[((size_t)(g * NCHUNK + c) * 64 + qr) * D + d]);
  float o = acc / fmaxf(Lsum, 1e-20f);
  int h = g * 4 + (qr >> 4), l = qr & 15;
  attnbf[(size_t)l * 4096 + h * 128 + d] = f2bf(o);
}

// ---------- output projection: wo read f32 directly, reg-staged ----------
__launch_bounds__(256)
__global__ void k_out_gemm(const unsigned short* __restrict__ attnbf,
                           const float* __restrict__ wo,
                           float* __restrict__ part_out) {
  const int ntile = blockIdx.x;
  const int ksp = blockIdx.y;
  const int tid = threadIdx.x, lane = tid & 63, w = tid >> 6;
  __shared__ __align__(16) unsigned char Asm[2048];
  __shared__ __align__(16) unsigned char Bsm[16384];

  f32x4 zf = {0.f, 0.f, 0.f, 0.f};
  f32x4 acc[2] = {zf, zf};
  for (int it = 0; it < 4; ++it) {
    if (w < 2) {
      int sl = w * 64 + lane;
      gl_lds16(attnbf + (size_t)(sl >> 3) * 4096 + ksp * 256 + it * 64 + (sl & 7) * 8, Asm + w * 1024);
    }
#pragma unroll
    for (int q = 0; q < 4; ++q) {
      int sl = (w * 4 + q) * 64 + lane;
      int row = sl >> 3, c0 = (sl & 7) * 8;
      float v8[8];
      ld8f(wo + (size_t)(ntile * 128 + row) * 4096 + ksp * 256 + it * 64 + c0, v8);
      st8lds((unsigned short*)Bsm + row * 64 + c0, v8);
    }
    __syncthreads();
#pragma unroll
    for (int ks = 0; ks < 2; ++ks) {
      bf16x8 a = *(const bf16x8*)(Asm + (lane & 15) * 128 + ks * 64 + (lane >> 4) * 16);
#pragma unroll
      for (int j = 0; j < 2; ++j) {
        int nr = w * 32 + j * 16 + (lane & 15);
        bf16x8 b = *(const bf16x8*)(Bsm + nr * 128 + ks * 64 + (lane >> 4) * 16);
        acc[j] = __builtin_amdgcn_mfma_f32_16x16x32_bf16(a, b, acc[j], 0, 0, 0);
      }
    }
    __syncthreads();
  }
#pragma unroll
  for (int j = 0; j < 2; ++j)
#pragma unroll
    for (int e = 0; e < 4; ++e) {
      int lq = (lane >> 4) * 4 + e;
      int n = ntile * 128 + w * 32 + j * 16 + (lane & 15);
      part_out[(size_t)ksp * 32768 + lq * 2048 + n] = acc[j][e];
    }
}

__global__ void k_out_combine(const float* __restrict__ part_out, float* __restrict__ out0) {
  int i = blockIdx.x * 256 + threadIdx.x;
  if (i < 32768) {
    float v = 0;
    for (int c = 0; c < 16; ++c) v += part_out[c * 32768 + i];
    out0[i] = v;
  }
}

extern "C" void kernel_launch(void* const* d_in, const int* in_sizes, int n_in,
                              void* d_out, int out_size, void* d_ws, size_t ws_size,
                              hipStream_t stream) {
  const float* x     = (const float*)d_in[0];
  const float* x_ctx = (const float*)d_in[1];
  const float* cos_q = (const float*)d_in[2];
  const float* sin_q = (const float*)d_in[3];
  const float* cos_k = (const float*)d_in[4];
  const float* sin_k = (const float*)d_in[5];
  const float* kv    = (const float*)d_in[6];
  const float* mask  = (const float*)d_in[7];
  const float* wq    = (const float*)d_in[8];
  const float* wk    = (const float*)d_in[9];
  const float* wv    = (const float*)d_in[10];
  const float* wo    = (const float*)d_in[11];
  const float* qn_w  = (const float*)d_in[12];
  const float* kn_w  = (const float*)d_in[13];
  const int* cur_pos = (const int*)d_in[14];

  float* out0 = (float*)d_out;
  float* cache = out0 + 32768;

  uint8_t* ws = (uint8_t*)d_ws;
  unsigned short* xc_bf  = (unsigned short*)(ws);               // 0x810000
  unsigned short* wk_bf  = (unsigned short*)(ws + 0x0810000);   // 0x400000
  unsigned short* wv_bf  = (unsigned short*)(ws + 0x0C10000);   // 0x400000
  float* qpart           = (float*)(ws + 0x1010000);            // 0x400000
  unsigned short* qbf    = (unsigned short*)(ws + 0x1410000);   // 0x20000
  unsigned short* attnbf = (unsigned short*)(ws + 0x1430000);   // 0x20000
  unsigned short* part_O = (unsigned short*)(ws + 0x1450000);   // 0xC00000
  float* part_m          = (float*)(ws + 0x2050000);            // 0x30000
  float* part_l          = (float*)(ws + 0x2090000);            // 0x30000
  float* part_out        = (float*)(ws + 0x20D0000);            // 0x200000

  unsigned short* xq_bf = xc_bf + (size_t)2048 * H;

  k_conv<<<dim3(4112), dim3(256), 0, stream>>>(wk, wv, x_ctx, x, wk_bf, wv_bf, xc_bf);
  k_q_proj<<<dim3(32, 16), dim3(256), 0, stream>>>(xq_bf, wq, qpart);
  k_q_fin<<<dim3(512), dim3(128), 0, stream>>>(qpart, qn_w, cos_q, sin_q, qbf);
  k_kv_gemm<<<dim3(16, 33), dim3(256), 0, stream>>>(xc_bf, wk_bf, wv_bf, kn_w, cos_k, sin_k, cur_pos, cache);
  k_attn<<<dim3(8, NCHUNK), dim3(256), 0, stream>>>(kv, cache, qbf, mask, cur_pos, part_O, part_m, part_l);
  k_attn_reduce<<<dim3(512), dim3(128), 0, stream>>>(part_O, part_m, part_l, attnbf);
  k_out_gemm<<<dim3(16, 16), dim3(256), 0, stream>>>(attnbf, wo, part_out);
  k_out_combine<<<dim3(128), dim3(256), 0, stream>>>(part_out, out0);
}

// Round 13
// 218.491 us; speedup vs baseline: 1.1900x; 1.0016x over previous
//
#include <hip/hip_runtime.h>
#include <hip/hip_bf16.h>
#include <stdint.h>

#define H 2048
#define L 16
#define D 128
#define NH 32
#define NKV 8
#define SL 32768
#define T_TOT 2064
#define EPS 1e-6f
#define SCALE 0.08838834764831845f
#define NCHUNK 96

typedef __bf16 bf16x8 __attribute__((ext_vector_type(8)));
typedef float f32x4 __attribute__((ext_vector_type(4)));

__device__ __forceinline__ float bf2f(unsigned short u) {
  union { uint32_t i; float f; } v; v.i = ((uint32_t)u) << 16; return v.f;
}
__device__ __forceinline__ unsigned short f2bf(float f) {
  union { float f; uint32_t i; } v; v.f = f;
  uint32_t u = v.i;
  return (unsigned short)((u + 0x7FFFu + ((u >> 16) & 1u)) >> 16);
}
__device__ __forceinline__ void ld8f(const float* p, float* o) {
  float4 a = *(const float4*)p;
  float4 b = *(const float4*)(p + 4);
  o[0]=a.x; o[1]=a.y; o[2]=a.z; o[3]=a.w;
  o[4]=b.x; o[5]=b.y; o[6]=b.z; o[7]=b.w;
}
__device__ __forceinline__ void st8lds(unsigned short* d, const float* v) {
  unsigned short t[8];
#pragma unroll
  for (int j = 0; j < 8; ++j) t[j] = f2bf(v[j]);
  *(uint4*)d = *(const uint4*)t;
}
__device__ __forceinline__ void gl_lds16(const void* g, void* l) {
  __builtin_amdgcn_global_load_lds(
      (const __attribute__((address_space(1))) void*)g,
      (__attribute__((address_space(3))) void*)l, 16, 0, 0);
}
// Raw barrier: LDS-visibility only; global loads/stores stay in flight (T4).
__device__ __forceinline__ void lds_barrier() {
  __builtin_amdgcn_sched_barrier(0);
  asm volatile("s_waitcnt lgkmcnt(0)");
  __builtin_amdgcn_s_barrier();
  __builtin_amdgcn_sched_barrier(0);
}

// ---------- f32 -> bf16 conversion (only multi-read tensors: wk, wv, x_ctx, x) ----------
__global__ void k_conv(const float* __restrict__ wk, const float* __restrict__ wv,
                       const float* __restrict__ x_ctx, const float* __restrict__ x,
                       unsigned short* __restrict__ wk_bf, unsigned short* __restrict__ wv_bf,
                       unsigned short* __restrict__ xc_bf) {
  size_t li = (size_t)blockIdx.x * 256 + threadIdx.x;
  const float* src; unsigned short* dst;
  if (li < 262144) { src = wk; dst = wk_bf; }
  else if ((li -= 262144) < 262144) { src = wv; dst = wv_bf; }
  else if ((li -= 262144) < 524288) { src = x_ctx; dst = xc_bf; }
  else if ((li -= 524288) < 4096) { src = x; dst = xc_bf + (size_t)2048 * H; }
  else return;
  float v8[8];
  ld8f(src + li * 8, v8);
  unsigned short t[8];
#pragma unroll
  for (int j = 0; j < 8; ++j) t[j] = f2bf(v8[j]);
  *(uint4*)(dst + li * 8) = *(const uint4*)t;
}

// ---------- Q projection: wq read f32 directly (use-once), reg-staged to bf16 LDS ----------
__launch_bounds__(256)
__global__ void k_q_proj(const unsigned short* __restrict__ xq_bf,
                         const float* __restrict__ wq,
                         float* __restrict__ qpart) {
  const int h = blockIdx.x, s = blockIdx.y;
  const int tid = threadIdx.x, lane = tid & 63, w = tid >> 6;
  __shared__ __align__(16) unsigned char Asm[2048];
  __shared__ __align__(16) unsigned char Bsm[16384];
  f32x4 zf = {0.f, 0.f, 0.f, 0.f};
  f32x4 acc[2] = {zf, zf};
  for (int kt = 0; kt < 2; ++kt) {
    if (w < 2) {
      int sl = w * 64 + lane;
      gl_lds16(xq_bf + (size_t)(sl >> 3) * H + s * 128 + kt * 64 + (sl & 7) * 8, Asm + w * 1024);
    }
#pragma unroll
    for (int q = 0; q < 4; ++q) {
      int sl = (w * 4 + q) * 64 + lane;
      int row = sl >> 3, c0 = (sl & 7) * 8;
      float v8[8];
      ld8f(wq + (size_t)(h * 128 + row) * H + s * 128 + kt * 64 + c0, v8);
      st8lds((unsigned short*)Bsm + row * 64 + c0, v8);
    }
    __syncthreads();
#pragma unroll
    for (int ks = 0; ks < 2; ++ks) {
      bf16x8 a = *(const bf16x8*)(Asm + (lane & 15) * 128 + ks * 64 + (lane >> 4) * 16);
#pragma unroll
      for (int j = 0; j < 2; ++j) {
        int nr = w * 32 + j * 16 + (lane & 15);
        bf16x8 b = *(const bf16x8*)(Bsm + nr * 128 + ks * 64 + (lane >> 4) * 16);
        acc[j] = __builtin_amdgcn_mfma_f32_16x16x32_bf16(a, b, acc[j], 0, 0, 0);
      }
    }
    __syncthreads();
  }
#pragma unroll
  for (int j = 0; j < 2; ++j)
#pragma unroll
    for (int e = 0; e < 4; ++e) {
      int lq = (lane >> 4) * 4 + e;
      int col = w * 32 + j * 16 + (lane & 15);
      qpart[((size_t)(s * NH + h) * L + lq) * D + col] = acc[j][e];
    }
}

// ---------- Q finalize ----------
__global__ void k_q_fin(const float* __restrict__ qpart, const float* __restrict__ qn_w,
                        const float* __restrict__ cos_q, const float* __restrict__ sin_q,
                        unsigned short* __restrict__ qbf) {
  const int head = blockIdx.x >> 4;
  const int l = blockIdx.x & 15;
  const int d = threadIdx.x;
  __shared__ float ybuf[128];
  __shared__ float red[4];
  float v = 0;
  for (int s = 0; s < 16; ++s) v += qpart[((size_t)(s * NH + head) * L + l) * D + d];
  float s1 = v, s2 = v * v;
  for (int m = 1; m < 64; m <<= 1) { s1 += __shfl_xor(s1, m); s2 += __shfl_xor(s2, m); }
  if ((threadIdx.x & 63) == 0) { red[(threadIdx.x >> 6) * 2] = s1; red[(threadIdx.x >> 6) * 2 + 1] = s2; }
  __syncthreads();
  float sum = red[0] + red[2], sumsq = red[1] + red[3];
  float mean = sum * (1.0f / 128.0f);
  float var = sumsq * (1.0f / 128.0f) - mean * mean;
  float rs = rsqrtf(fmaxf(var, 0.f) + EPS);
  float z = (v - mean) * rs * qn_w[d];
  ybuf[d] = z;
  __syncthreads();
  float zp = ybuf[d ^ 64];
  float rot = (d < 64) ? -zp : zp;
  float o = z * cos_q[l * D + d] + rot * sin_q[l * D + d];
  qbf[(size_t)(head * L + l) * D + d] = f2bf(o);
}

// ---------- KV projection GEMM: BM=64, grid (16,33)=528 blocks (~2/CU) ----------
__launch_bounds__(256)
__global__ void k_kv_gemm(const unsigned short* __restrict__ xc_bf,
                          const unsigned short* __restrict__ wk_bf,
                          const unsigned short* __restrict__ wv_bf,
                          const float* __restrict__ kn_w,
                          const float* __restrict__ cos_k, const float* __restrict__ sin_k,
                          const int* __restrict__ cur_pos, float* __restrict__ cache) {
  const int bn = blockIdx.x;
  const int bm = blockIdx.y;
  const int tid = threadIdx.x, lane = tid & 63, wid = tid >> 6;
  const int wm = wid >> 1, wn = wid & 1;

  __shared__ __align__(16) unsigned char smem[33536];
  unsigned char* A = smem;
  unsigned char* B = smem + 8192;

  const unsigned short* wsrc = (bn < 8) ? wk_bf + (size_t)(bn * 128) * H
                                        : wv_bf + (size_t)((bn - 8) * 128) * H;
  int arow[2], ac8[2], brow[4], bc8[4];
#pragma unroll
  for (int q = 0; q < 2; ++q) {
    int sl = (wid * 2 + q) * 64 + lane;
    int t = bm * 64 + (sl >> 3); if (t > 2063) t = 2063;
    arow[q] = t; ac8[q] = (sl & 7) * 8;
  }
#pragma unroll
  for (int q = 0; q < 4; ++q) {
    int sl = (wid * 4 + q) * 64 + lane;
    brow[q] = sl >> 3; bc8[q] = (sl & 7) * 8;
  }

  f32x4 acc[2][4];
  f32x4 zf = {0.f, 0.f, 0.f, 0.f};
#pragma unroll
  for (int i = 0; i < 2; ++i)
#pragma unroll
    for (int j = 0; j < 4; ++j) acc[i][j] = zf;

  for (int kt = 0; kt < H / 64; ++kt) {
#pragma unroll
    for (int q = 0; q < 2; ++q)
      gl_lds16(xc_bf + (size_t)arow[q] * H + kt * 64 + ac8[q], A + (wid * 2 + q) * 1024);
#pragma unroll
    for (int q = 0; q < 4; ++q)
      gl_lds16(wsrc + (size_t)brow[q] * H + kt * 64 + bc8[q], B + (wid * 4 + q) * 1024);
    __syncthreads();
#pragma unroll
    for (int ks = 0; ks < 2; ++ks) {
      bf16x8 a[2], b[4];
#pragma unroll
      for (int i = 0; i < 2; ++i) {
        int row = wm * 32 + i * 16 + (lane & 15);
        a[i] = *(const bf16x8*)(A + row * 128 + ks * 64 + (lane >> 4) * 16);
      }
#pragma unroll
      for (int j = 0; j < 4; ++j) {
        int nr = wn * 64 + j * 16 + (lane & 15);
        b[j] = *(const bf16x8*)(B + nr * 128 + ks * 64 + (lane >> 4) * 16);
      }
#pragma unroll
      for (int i = 0; i < 2; ++i)
#pragma unroll
        for (int j = 0; j < 4; ++j)
          acc[i][j] = __builtin_amdgcn_mfma_f32_16x16x32_bf16(a[i], b[j], acc[i][j], 0, 0, 0);
    }
    __syncthreads();
  }

  float* cs = (float*)smem;                 // [64][129] f32
  float* lnp = (float*)(smem + 33024);      // [64][2]
  const int pos0 = *cur_pos;
#pragma unroll
  for (int i = 0; i < 2; ++i)
#pragma unroll
    for (int j = 0; j < 4; ++j)
#pragma unroll
      for (int e = 0; e < 4; ++e) {
        int r = wm * 32 + i * 16 + (lane >> 4) * 4 + e;
        int c = wn * 64 + j * 16 + (lane & 15);
        cs[r * 129 + c] = acc[i][j][e];
      }
  __syncthreads();
  if (bn < 8 && tid < 64) {
    int r = tid;
    float sum = 0, sumsq = 0;
    for (int d2 = 0; d2 < 128; ++d2) { float v = cs[r * 129 + d2]; sum += v; sumsq += v * v; }
    float mean = sum * (1.0f / 128.0f);
    float var = sumsq * (1.0f / 128.0f) - mean * mean;
    lnp[r * 2] = mean;
    lnp[r * 2 + 1] = rsqrtf(fmaxf(var, 0.f) + EPS);
  }
  __syncthreads();
  {
    int r = tid >> 2, q = tid & 3;
    int t = bm * 64 + r;
    if (t < T_TOT) {
      if (bn < 8) {
        float mean = lnp[r * 2], rs = lnp[r * 2 + 1];
        float* dst = cache + ((size_t)bn * SL + (size_t)(pos0 + t)) * D;
#pragma unroll
        for (int i8 = 0; i8 < 8; ++i8) {
          int d2 = q * 32 + i8 * 4;
          float4 o4;
          float* o = (float*)&o4;
#pragma unroll
          for (int e = 0; e < 4; ++e) {
            int dd = d2 + e;
            float z = (cs[r * 129 + dd] - mean) * rs * kn_w[dd];
            int p = dd ^ 64;
            float zp = (cs[r * 129 + p] - mean) * rs * kn_w[p];
            float rot = (dd < 64) ? -zp : zp;
            o[e] = z * cos_k[(size_t)t * D + dd] + rot * sin_k[(size_t)t * D + dd];
          }
          *(float4*)(dst + d2) = o4;
        }
      } else {
        float* dst = cache + ((size_t)(NKV + (bn - 8)) * SL + (size_t)(pos0 + t)) * D;
#pragma unroll
        for (int i8 = 0; i8 < 8; ++i8) {
          int d2 = q * 32 + i8 * 4;
          float4 o4 = { cs[r * 129 + d2], cs[r * 129 + d2 + 1], cs[r * 129 + d2 + 2], cs[r * 129 + d2 + 3] };
          *(float4*)(dst + d2) = o4;
        }
      }
    }
  }
}

// ---------- fused flash attention + cache pass-through (raw LDS-only barriers) ----------
__launch_bounds__(256)
__global__ void k_attn(const float* __restrict__ kv_src, float* __restrict__ cache,
                       const unsigned short* __restrict__ qbf, const float* __restrict__ mask,
                       const int* __restrict__ cur_pos,
                       unsigned short* __restrict__ part_O,
                       float* __restrict__ part_m, float* __restrict__ part_l) {
  const int g = blockIdx.x;   // kv head
  const int ch = blockIdx.y;  // 0..95
  const int tid = threadIdx.x, lane = tid & 63, w = tid >> 6;
  const int t0 = ch * 5 + (ch < 32 ? ch : 32);
  const int t1 = t0 + 5 + (ch < 32 ? 1 : 0);
  const int pos0 = *cur_pos, pos1 = pos0 + T_TOT;

  __shared__ __align__(16) unsigned short Klds[64 * 136];
  __shared__ __align__(16) unsigned short Vt[128 * 72];
  __shared__ __align__(16) unsigned short Plds[4 * 16 * 72];

  bf16x8 qf[4];
#pragma unroll
  for (int ks = 0; ks < 4; ++ks)
    qf[ks] = *(const bf16x8*)(qbf + ((size_t)(g * 4 + w) * L + (lane & 15)) * D + ks * 32 + (lane >> 4) * 8);

  f32x4 O[8];
  f32x4 zf = {0.f, 0.f, 0.f, 0.f};
#pragma unroll
  for (int j = 0; j < 8; ++j) O[j] = zf;
  float mrow[4] = {-1e30f, -1e30f, -1e30f, -1e30f};
  float lrow[4] = {0, 0, 0, 0};
  unsigned short* Pw = Plds + w * 16 * 72;

  float4 ka[4], kb[4], va[4], vb[4];
  float mrgC[16], mrgN[16];
  int pp[4];

#define LOADT(ti_) do {                                                         \
    _Pragma("unroll")                                                           \
    for (int g2 = 0; g2 < 4; ++g2) {                                            \
      int slot = tid + g2 * 256;                                                \
      int pos = slot >> 4, c0 = (slot & 15) * 8;                                \
      int p = (ti_) * 64 + pos;                                                 \
      pp[g2] = p;                                                               \
      bool u = (p >= pos0) & (p < pos1);                                        \
      const float* sp = u ? cache : kv_src;                                     \
      size_t kidx = ((size_t)g * SL + p) * D + c0;                              \
      size_t vidx = ((size_t)(NKV + g) * SL + p) * D + c0;                      \
      ka[g2] = *(const float4*)(sp + kidx);                                     \
      kb[g2] = *(const float4*)(sp + kidx + 4);                                 \
      va[g2] = *(const float4*)(sp + vidx);                                     \
      vb[g2] = *(const float4*)(sp + vidx + 4);                                 \
    }                                                                           \
    _Pragma("unroll")                                                           \
    for (int ee = 0; ee < 4; ++ee)                                              \
      _Pragma("unroll")                                                         \
      for (int nf2 = 0; nf2 < 4; ++nf2)                                         \
        mrgN[ee * 4 + nf2] = mask[(size_t)((lane >> 4) * 4 + ee) * SL +         \
                                  (ti_) * 64 + nf2 * 16 + (lane & 15)];         \
  } while (0)

#define WRITET() do {                                                           \
    _Pragma("unroll")                                                           \
    for (int g2 = 0; g2 < 4; ++g2) {                                            \
      int slot = tid + g2 * 256;                                                \
      int pos = slot >> 4, c0 = (slot & 15) * 8;                                \
      int p = pp[g2];                                                           \
      bool u = (p >= pos0) & (p < pos1);                                        \
      if (!u) {                                                                 \
        size_t kidx = ((size_t)g * SL + p) * D + c0;                            \
        size_t vidx = ((size_t)(NKV + g) * SL + p) * D + c0;                    \
        *(float4*)(cache + kidx) = ka[g2];                                      \
        *(float4*)(cache + kidx + 4) = kb[g2];                                  \
        *(float4*)(cache + vidx) = va[g2];                                      \
        *(float4*)(cache + vidx + 4) = vb[g2];                                  \
      }                                                                         \
      float kf[8] = {ka[g2].x, ka[g2].y, ka[g2].z, ka[g2].w,                    \
                     kb[g2].x, kb[g2].y, kb[g2].z, kb[g2].w};                   \
      st8lds(Klds + pos * 136 + c0, kf);                                        \
      float vf[8] = {va[g2].x, va[g2].y, va[g2].z, va[g2].w,                    \
                     vb[g2].x, vb[g2].y, vb[g2].z, vb[g2].w};                   \
      _Pragma("unroll")                                                         \
      for (int jj = 0; jj < 8; ++jj) {                                          \
        int dd = c0 + jj;                                                       \
        Vt[dd * 72 + (pos ^ (((dd >> 3) & 7) << 3))] = f2bf(vf[jj]);            \
      }                                                                         \
    }                                                                           \
  } while (0)

  LOADT(t0);
  for (int ti = t0; ti < t1; ++ti) {
    WRITET();
#pragma unroll
    for (int ii = 0; ii < 16; ++ii) mrgC[ii] = mrgN[ii];
    if (ti + 1 < t1) LOADT(ti + 1);
    lds_barrier();  // stores + prefetch loads stay in flight

    // ---- QK^T ----
    f32x4 Sv[4];
#pragma unroll
    for (int nf = 0; nf < 4; ++nf) {
      f32x4 accs = zf;
#pragma unroll
      for (int ks = 0; ks < 4; ++ks) {
        int pl = nf * 16 + (lane & 15);
        bf16x8 bk = *(const bf16x8*)(Klds + pl * 136 + ks * 32 + (lane >> 4) * 8);
        accs = __builtin_amdgcn_mfma_f32_16x16x32_bf16(qf[ks], bk, accs, 0, 0, 0);
      }
      Sv[nf] = accs;
    }

    // ---- online softmax ----
#pragma unroll
    for (int e = 0; e < 4; ++e) {
      int lq = (lane >> 4) * 4 + e;
      float sc[4];
#pragma unroll
      for (int nf = 0; nf < 4; ++nf)
        sc[nf] = Sv[nf][e] * SCALE + mrgC[e * 4 + nf];
      float tmax = fmaxf(fmaxf(sc[0], sc[1]), fmaxf(sc[2], sc[3]));
#pragma unroll
      for (int mm = 1; mm < 16; mm <<= 1) tmax = fmaxf(tmax, __shfl_xor(tmax, mm));
      float mnew = fmaxf(mrow[e], tmax);
      float alpha = __expf(mrow[e] - mnew);
      float psum = 0;
#pragma unroll
      for (int nf = 0; nf < 4; ++nf) {
        float p = __expf(sc[nf] - mnew);
        psum += p;
        Pw[lq * 72 + nf * 16 + (lane & 15)] = f2bf(p);
      }
#pragma unroll
      for (int mm = 1; mm < 16; mm <<= 1) psum += __shfl_xor(psum, mm);
      lrow[e] = lrow[e] * alpha + psum;
      mrow[e] = mnew;
#pragma unroll
      for (int j = 0; j < 8; ++j) O[j][e] *= alpha;
    }

    // ---- PV ----
#pragma unroll
    for (int ks2 = 0; ks2 < 2; ++ks2) {
      bf16x8 ap = *(const bf16x8*)(Pw + (lane & 15) * 72 + ks2 * 32 + (lane >> 4) * 8);
#pragma unroll
      for (int jf = 0; jf < 8; ++jf) {
        int dd = jf * 16 + (lane & 15);
        int po = (ks2 * 32 + (lane >> 4) * 8) ^ (((dd >> 3) & 7) << 3);
        bf16x8 bv = *(const bf16x8*)(Vt + dd * 72 + po);
        O[jf] = __builtin_amdgcn_mfma_f32_16x16x32_bf16(ap, bv, O[jf], 0, 0, 0);
      }
    }
    lds_barrier();  // PV reads done; next WRITET may overwrite
  }
#undef LOADT
#undef WRITET

  const int cidx = g * NCHUNK + ch;
#pragma unroll
  for (int jf = 0; jf < 8; ++jf)
#pragma unroll
    for (int e = 0; e < 4; ++e) {
      int qr = w * 16 + (lane >> 4) * 4 + e;
      part_O[((size_t)cidx * 64 + qr) * D + jf * 16 + (lane & 15)] = f2bf(O[jf][e]);
    }
  if ((lane & 15) == 0) {
#pragma unroll
    for (int e = 0; e < 4; ++e) {
      int qr = w * 16 + (lane >> 4) * 4 + e;
      part_m[cidx * 64 + qr] = mrow[e];
      part_l[cidx * 64 + qr] = lrow[e];
    }
  }
}

// ---------- combine partials (block-cooperative M/Lsum, weights cached in LDS) ----------
__global__ void k_attn_reduce(const unsigned short* __restrict__ part_O,
                              const float* __restrict__ part_m,
                              const float* __restrict__ part_l,
                              unsigned short* __restrict__ attnbf) {
  const int g = blockIdx.x >> 6;
  const int qr = blockIdx.x & 63;
  const int d = threadIdx.x;  // 128 threads
  __shared__ float Wlds[NCHUNK];
  __shared__ float rmax[2];
  __shared__ float rsum[2];

  float mv = (d < NCHUNK) ? part_m[(g * NCHUNK + d) * 64 + qr] : -1e30f;
  float t = mv;
  for (int mm = 1; mm < 64; mm <<= 1) t = fmaxf(t, __shfl_xor(t, mm));
  if ((d & 63) == 0) rmax[d >> 6] = t;
  __syncthreads();
  float M = fmaxf(rmax[0], rmax[1]);

  float wgt = (d < NCHUNK) ? __expf(mv - M) : 0.f;
  float lv = (d < NCHUNK) ? part_l[(g * NCHUNK + d) * 64 + qr] * wgt : 0.f;
  if (d < NCHUNK) Wlds[d] = wgt;
  float s = lv;
  for (int mm = 1; mm < 64; mm <<= 1) s += __shfl_xor(s, mm);
  if ((d & 63) == 0) rsum[d >> 6] = s;
  __syncthreads();
  float Lsum = rsum[0] + rsum[1];

  float acc = 0;
  for (int c = 0; c < NCHUNK; ++c)
    acc += Wlds[c] * bf2f(part_O[((size_t)(g * NCHUNK + c) * 64 + qr) * D + d]);
  float o = acc / fmaxf(Lsum, 1e-20f);
  int h = g * 4 + (qr >> 4), l = qr & 15;
  attnbf[(size_t)l * 4096 + h * 128 + d] = f2bf(o);
}

// ---------- output projection: wo read f32 directly, reg-staged ----------
__launch_bounds__(256)
__global__ void k_out_gemm(const unsigned short* __restrict__ attnbf,
                           const float* __restrict__ wo,
                           float* __restrict__ part_out) {
  const int ntile = blockIdx.x;
  const int ksp = blockIdx.y;
  const int tid = threadIdx.x, lane = tid & 63, w = tid >> 6;
  __shared__ __align__(16) unsigned char Asm[2048];
  __shared__ __align__(16) unsigned char Bsm[16384];

  f32x4 zf = {0.f, 0.f, 0.f, 0.f};
  f32x4 acc[2] = {zf, zf};
  for (int it = 0; it < 4; ++it) {
    if (w < 2) {
      int sl = w * 64 + lane;
      gl_lds16(attnbf + (size_t)(sl >> 3) * 4096 + ksp * 256 + it * 64 + (sl & 7) * 8, Asm + w * 1024);
    }
#pragma unroll
    for (int q = 0; q < 4; ++q) {
      int sl = (w * 4 + q) * 64 + lane;
      int row = sl >> 3, c0 = (sl & 7) * 8;
      float v8[8];
      ld8f(wo + (size_t)(ntile * 128 + row) * 4096 + ksp * 256 + it * 64 + c0, v8);
      st8lds((unsigned short*)Bsm + row * 64 + c0, v8);
    }
    __syncthreads();
#pragma unroll
    for (int ks = 0; ks < 2; ++ks) {
      bf16x8 a = *(const bf16x8*)(Asm + (lane & 15) * 128 + ks * 64 + (lane >> 4) * 16);
#pragma unroll
      for (int j = 0; j < 2; ++j) {
        int nr = w * 32 + j * 16 + (lane & 15);
        bf16x8 b = *(const bf16x8*)(Bsm + nr * 128 + ks * 64 + (lane >> 4) * 16);
        acc[j] = __builtin_amdgcn_mfma_f32_16x16x32_bf16(a, b, acc[j], 0, 0, 0);
      }
    }
    __syncthreads();
  }
#pragma unroll
  for (int j = 0; j < 2; ++j)
#pragma unroll
    for (int e = 0; e < 4; ++e) {
      int lq = (lane >> 4) * 4 + e;
      int n = ntile * 128 + w * 32 + j * 16 + (lane & 15);
      part_out[(size_t)ksp * 32768 + lq * 2048 + n] = acc[j][e];
    }
}

__global__ void k_out_combine(const float* __restrict__ part_out, float* __restrict__ out0) {
  int i = blockIdx.x * 256 + threadIdx.x;
  if (i < 32768) {
    float v = 0;
    for (int c = 0; c < 16; ++c) v += part_out[c * 32768 + i];
    out0[i] = v;
  }
}

extern "C" void kernel_launch(void* const* d_in, const int* in_sizes, int n_in,
                              void* d_out, int out_size, void* d_ws, size_t ws_size,
                              hipStream_t stream) {
  const float* x     = (const float*)d_in[0];
  const float* x_ctx = (const float*)d_in[1];
  const float* cos_q = (const float*)d_in[2];
  const float* sin_q = (const float*)d_in[3];
  const float* cos_k = (const float*)d_in[4];
  const float* sin_k = (const float*)d_in[5];
  const float* kv    = (const float*)d_in[6];
  const float* mask  = (const float*)d_in[7];
  const float* wq    = (const float*)d_in[8];
  const float* wk    = (const float*)d_in[9];
  const float* wv    = (const float*)d_in[10];
  const float* wo    = (const float*)d_in[11];
  const float* qn_w  = (const float*)d_in[12];
  const float* kn_w  = (const float*)d_in[13];
  const int* cur_pos = (const int*)d_in[14];

  float* out0 = (float*)d_out;
  float* cache = out0 + 32768;

  uint8_t* ws = (uint8_t*)d_ws;
  unsigned short* xc_bf  = (unsigned short*)(ws);               // 0x810000
  unsigned short* wk_bf  = (unsigned short*)(ws + 0x0810000);   // 0x400000
  unsigned short* wv_bf  = (unsigned short*)(ws + 0x0C10000);   // 0x400000
  float* qpart           = (float*)(ws + 0x1010000);            // 0x400000
  unsigned short* qbf    = (unsigned short*)(ws + 0x1410000);   // 0x20000
  unsigned short* attnbf = (unsigned short*)(ws + 0x1430000);   // 0x20000
  unsigned short* part_O = (unsigned short*)(ws + 0x1450000);   // 0xC00000
  float* part_m          = (float*)(ws + 0x2050000);            // 0x30000
  float* part_l          = (float*)(ws + 0x2090000);            // 0x30000
  float* part_out        = (float*)(ws + 0x20D0000);            // 0x200000

  unsigned short* xq_bf = xc_bf + (size_t)2048 * H;

  k_conv<<<dim3(4112), dim3(256), 0, stream>>>(wk, wv, x_ctx, x, wk_bf, wv_bf, xc_bf);
  k_q_proj<<<dim3(32, 16), dim3(256), 0, stream>>>(xq_bf, wq, qpart);
  k_q_fin<<<dim3(512), dim3(128), 0, stream>>>(qpart, qn_w, cos_q, sin_q, qbf);
  k_kv_gemm<<<dim3(16, 33), dim3(256), 0, stream>>>(xc_bf, wk_bf, wv_bf, kn_w, cos_k, sin_k, cur_pos, cache);
  k_attn<<<dim3(8, NCHUNK), dim3(256), 0, stream>>>(kv, cache, qbf, mask, cur_pos, part_O, part_m, part_l);
  k_attn_reduce<<<dim3(512), dim3(128), 0, stream>>>(part_O, part_m, part_l, attnbf);
  k_out_gemm<<<dim3(16, 16), dim3(256), 0, stream>>>(attnbf, wo, part_out);
  k_out_combine<<<dim3(128), dim3(256), 0, stream>>>(part_out, out0);
}

// Round 14
// 216.124 us; speedup vs baseline: 1.2031x; 1.0110x over previous
//
#include <hip/hip_runtime.h>
#include <hip/hip_bf16.h>
#include <stdint.h>

#define H 2048
#define L 16
#define D 128
#define NH 32
#define NKV 8
#define SL 32768
#define T_TOT 2064
#define EPS 1e-6f
#define SCALE 0.08838834764831845f
#define NCHUNK 96

typedef __bf16 bf16x8 __attribute__((ext_vector_type(8)));
typedef float f32x4 __attribute__((ext_vector_type(4)));

__device__ __forceinline__ float bf2f(unsigned short u) {
  union { uint32_t i; float f; } v; v.i = ((uint32_t)u) << 16; return v.f;
}
// Native conversion: compiler emits v_cvt_pk_bf16_f32 pairs on gfx950 (RNE).
__device__ __forceinline__ unsigned short f2bf(float f) {
  __bf16 h = (__bf16)f;
  union { __bf16 h; unsigned short u; } v; v.h = h; return v.u;
}
__device__ __forceinline__ void ld8f(const float* p, float* o) {
  float4 a = *(const float4*)p;
  float4 b = *(const float4*)(p + 4);
  o[0]=a.x; o[1]=a.y; o[2]=a.z; o[3]=a.w;
  o[4]=b.x; o[5]=b.y; o[6]=b.z; o[7]=b.w;
}
__device__ __forceinline__ void st8lds(unsigned short* d, const float* v) {
  unsigned short t[8];
#pragma unroll
  for (int j = 0; j < 8; ++j) t[j] = f2bf(v[j]);
  *(uint4*)d = *(const uint4*)t;
}
__device__ __forceinline__ void gl_lds16(const void* g, void* l) {
  __builtin_amdgcn_global_load_lds(
      (const __attribute__((address_space(1))) void*)g,
      (__attribute__((address_space(3))) void*)l, 16, 0, 0);
}
// Raw barrier: LDS-visibility only; global loads/stores stay in flight.
__device__ __forceinline__ void lds_barrier() {
  __builtin_amdgcn_sched_barrier(0);
  asm volatile("s_waitcnt lgkmcnt(0)");
  __builtin_amdgcn_s_barrier();
  __builtin_amdgcn_sched_barrier(0);
}

// ---------- f32 -> bf16 conversion (only multi-read tensors: wk, wv, x_ctx, x) ----------
__global__ void k_conv(const float* __restrict__ wk, const float* __restrict__ wv,
                       const float* __restrict__ x_ctx, const float* __restrict__ x,
                       unsigned short* __restrict__ wk_bf, unsigned short* __restrict__ wv_bf,
                       unsigned short* __restrict__ xc_bf) {
  size_t li = (size_t)blockIdx.x * 256 + threadIdx.x;
  const float* src; unsigned short* dst;
  if (li < 262144) { src = wk; dst = wk_bf; }
  else if ((li -= 262144) < 262144) { src = wv; dst = wv_bf; }
  else if ((li -= 262144) < 524288) { src = x_ctx; dst = xc_bf; }
  else if ((li -= 524288) < 4096) { src = x; dst = xc_bf + (size_t)2048 * H; }
  else return;
  float v8[8];
  ld8f(src + li * 8, v8);
  unsigned short t[8];
#pragma unroll
  for (int j = 0; j < 8; ++j) t[j] = f2bf(v8[j]);
  *(uint4*)(dst + li * 8) = *(const uint4*)t;
}

// ---------- Q projection: wq read f32 directly (use-once), reg-staged to bf16 LDS ----------
__launch_bounds__(256)
__global__ void k_q_proj(const unsigned short* __restrict__ xq_bf,
                         const float* __restrict__ wq,
                         float* __restrict__ qpart) {
  const int h = blockIdx.x, s = blockIdx.y;
  const int tid = threadIdx.x, lane = tid & 63, w = tid >> 6;
  __shared__ __align__(16) unsigned char Asm[2048];
  __shared__ __align__(16) unsigned char Bsm[16384];
  f32x4 zf = {0.f, 0.f, 0.f, 0.f};
  f32x4 acc[2] = {zf, zf};
  for (int kt = 0; kt < 2; ++kt) {
    if (w < 2) {
      int sl = w * 64 + lane;
      gl_lds16(xq_bf + (size_t)(sl >> 3) * H + s * 128 + kt * 64 + (sl & 7) * 8, Asm + w * 1024);
    }
#pragma unroll
    for (int q = 0; q < 4; ++q) {
      int sl = (w * 4 + q) * 64 + lane;
      int row = sl >> 3, c0 = (sl & 7) * 8;
      float v8[8];
      ld8f(wq + (size_t)(h * 128 + row) * H + s * 128 + kt * 64 + c0, v8);
      st8lds((unsigned short*)Bsm + row * 64 + c0, v8);
    }
    __syncthreads();
#pragma unroll
    for (int ks = 0; ks < 2; ++ks) {
      bf16x8 a = *(const bf16x8*)(Asm + (lane & 15) * 128 + ks * 64 + (lane >> 4) * 16);
#pragma unroll
      for (int j = 0; j < 2; ++j) {
        int nr = w * 32 + j * 16 + (lane & 15);
        bf16x8 b = *(const bf16x8*)(Bsm + nr * 128 + ks * 64 + (lane >> 4) * 16);
        acc[j] = __builtin_amdgcn_mfma_f32_16x16x32_bf16(a, b, acc[j], 0, 0, 0);
      }
    }
    __syncthreads();
  }
#pragma unroll
  for (int j = 0; j < 2; ++j)
#pragma unroll
    for (int e = 0; e < 4; ++e) {
      int lq = (lane >> 4) * 4 + e;
      int col = w * 32 + j * 16 + (lane & 15);
      qpart[((size_t)(s * NH + h) * L + lq) * D + col] = acc[j][e];
    }
}

// ---------- Q finalize ----------
__global__ void k_q_fin(const float* __restrict__ qpart, const float* __restrict__ qn_w,
                        const float* __restrict__ cos_q, const float* __restrict__ sin_q,
                        unsigned short* __restrict__ qbf) {
  const int head = blockIdx.x >> 4;
  const int l = blockIdx.x & 15;
  const int d = threadIdx.x;
  __shared__ float ybuf[128];
  __shared__ float red[4];
  float v = 0;
  for (int s = 0; s < 16; ++s) v += qpart[((size_t)(s * NH + head) * L + l) * D + d];
  float s1 = v, s2 = v * v;
  for (int m = 1; m < 64; m <<= 1) { s1 += __shfl_xor(s1, m); s2 += __shfl_xor(s2, m); }
  if ((threadIdx.x & 63) == 0) { red[(threadIdx.x >> 6) * 2] = s1; red[(threadIdx.x >> 6) * 2 + 1] = s2; }
  __syncthreads();
  float sum = red[0] + red[2], sumsq = red[1] + red[3];
  float mean = sum * (1.0f / 128.0f);
  float var = sumsq * (1.0f / 128.0f) - mean * mean;
  float rs = rsqrtf(fmaxf(var, 0.f) + EPS);
  float z = (v - mean) * rs * qn_w[d];
  ybuf[d] = z;
  __syncthreads();
  float zp = ybuf[d ^ 64];
  float rot = (d < 64) ? -zp : zp;
  float o = z * cos_q[l * D + d] + rot * sin_q[l * D + d];
  qbf[(size_t)(head * L + l) * D + d] = f2bf(o);
}

// ---------- KV projection GEMM: BM=64, grid (16,33)=528 blocks (~2/CU) ----------
__launch_bounds__(256)
__global__ void k_kv_gemm(const unsigned short* __restrict__ xc_bf,
                          const unsigned short* __restrict__ wk_bf,
                          const unsigned short* __restrict__ wv_bf,
                          const float* __restrict__ kn_w,
                          const float* __restrict__ cos_k, const float* __restrict__ sin_k,
                          const int* __restrict__ cur_pos, float* __restrict__ cache) {
  const int bn = blockIdx.x;
  const int bm = blockIdx.y;
  const int tid = threadIdx.x, lane = tid & 63, wid = tid >> 6;
  const int wm = wid >> 1, wn = wid & 1;

  __shared__ __align__(16) unsigned char smem[33536];
  unsigned char* A = smem;
  unsigned char* B = smem + 8192;

  const unsigned short* wsrc = (bn < 8) ? wk_bf + (size_t)(bn * 128) * H
                                        : wv_bf + (size_t)((bn - 8) * 128) * H;
  int arow[2], ac8[2], brow[4], bc8[4];
#pragma unroll
  for (int q = 0; q < 2; ++q) {
    int sl = (wid * 2 + q) * 64 + lane;
    int t = bm * 64 + (sl >> 3); if (t > 2063) t = 2063;
    arow[q] = t; ac8[q] = (sl & 7) * 8;
  }
#pragma unroll
  for (int q = 0; q < 4; ++q) {
    int sl = (wid * 4 + q) * 64 + lane;
    brow[q] = sl >> 3; bc8[q] = (sl & 7) * 8;
  }

  f32x4 acc[2][4];
  f32x4 zf = {0.f, 0.f, 0.f, 0.f};
#pragma unroll
  for (int i = 0; i < 2; ++i)
#pragma unroll
    for (int j = 0; j < 4; ++j) acc[i][j] = zf;

  for (int kt = 0; kt < H / 64; ++kt) {
#pragma unroll
    for (int q = 0; q < 2; ++q)
      gl_lds16(xc_bf + (size_t)arow[q] * H + kt * 64 + ac8[q], A + (wid * 2 + q) * 1024);
#pragma unroll
    for (int q = 0; q < 4; ++q)
      gl_lds16(wsrc + (size_t)brow[q] * H + kt * 64 + bc8[q], B + (wid * 4 + q) * 1024);
    __syncthreads();
#pragma unroll
    for (int ks = 0; ks < 2; ++ks) {
      bf16x8 a[2], b[4];
#pragma unroll
      for (int i = 0; i < 2; ++i) {
        int row = wm * 32 + i * 16 + (lane & 15);
        a[i] = *(const bf16x8*)(A + row * 128 + ks * 64 + (lane >> 4) * 16);
      }
#pragma unroll
      for (int j = 0; j < 4; ++j) {
        int nr = wn * 64 + j * 16 + (lane & 15);
        b[j] = *(const bf16x8*)(B + nr * 128 + ks * 64 + (lane >> 4) * 16);
      }
#pragma unroll
      for (int i = 0; i < 2; ++i)
#pragma unroll
        for (int j = 0; j < 4; ++j)
          acc[i][j] = __builtin_amdgcn_mfma_f32_16x16x32_bf16(a[i], b[j], acc[i][j], 0, 0, 0);
    }
    __syncthreads();
  }

  float* cs = (float*)smem;                 // [64][129] f32
  float* lnp = (float*)(smem + 33024);      // [64][2]
  const int pos0 = *cur_pos;
#pragma unroll
  for (int i = 0; i < 2; ++i)
#pragma unroll
    for (int j = 0; j < 4; ++j)
#pragma unroll
      for (int e = 0; e < 4; ++e) {
        int r = wm * 32 + i * 16 + (lane >> 4) * 4 + e;
        int c = wn * 64 + j * 16 + (lane & 15);
        cs[r * 129 + c] = acc[i][j][e];
      }
  __syncthreads();
  if (bn < 8 && tid < 64) {
    int r = tid;
    float sum = 0, sumsq = 0;
    for (int d2 = 0; d2 < 128; ++d2) { float v = cs[r * 129 + d2]; sum += v; sumsq += v * v; }
    float mean = sum * (1.0f / 128.0f);
    float var = sumsq * (1.0f / 128.0f) - mean * mean;
    lnp[r * 2] = mean;
    lnp[r * 2 + 1] = rsqrtf(fmaxf(var, 0.f) + EPS);
  }
  __syncthreads();
  {
    int r = tid >> 2, q = tid & 3;
    int t = bm * 64 + r;
    if (t < T_TOT) {
      if (bn < 8) {
        float mean = lnp[r * 2], rs = lnp[r * 2 + 1];
        float* dst = cache + ((size_t)bn * SL + (size_t)(pos0 + t)) * D;
#pragma unroll
        for (int i8 = 0; i8 < 8; ++i8) {
          int d2 = q * 32 + i8 * 4;
          float4 o4;
          float* o = (float*)&o4;
#pragma unroll
          for (int e = 0; e < 4; ++e) {
            int dd = d2 + e;
            float z = (cs[r * 129 + dd] - mean) * rs * kn_w[dd];
            int p = dd ^ 64;
            float zp = (cs[r * 129 + p] - mean) * rs * kn_w[p];
            float rot = (dd < 64) ? -zp : zp;
            o[e] = z * cos_k[(size_t)t * D + dd] + rot * sin_k[(size_t)t * D + dd];
          }
          *(float4*)(dst + d2) = o4;
        }
      } else {
        float* dst = cache + ((size_t)(NKV + (bn - 8)) * SL + (size_t)(pos0 + t)) * D;
#pragma unroll
        for (int i8 = 0; i8 < 8; ++i8) {
          int d2 = q * 32 + i8 * 4;
          float4 o4 = { cs[r * 129 + d2], cs[r * 129 + d2 + 1], cs[r * 129 + d2 + 2], cs[r * 129 + d2 + 3] };
          *(float4*)(dst + d2) = o4;
        }
      }
    }
  }
}

// ---------- fused flash attention + cache pass-through ----------
__launch_bounds__(256)
__global__ void k_attn(const float* __restrict__ kv_src, float* __restrict__ cache,
                       const unsigned short* __restrict__ qbf, const float* __restrict__ mask,
                       const int* __restrict__ cur_pos,
                       unsigned short* __restrict__ part_O,
                       float* __restrict__ part_m, float* __restrict__ part_l) {
  const int g = blockIdx.x;   // kv head
  const int ch = blockIdx.y;  // 0..95
  const int tid = threadIdx.x, lane = tid & 63, w = tid >> 6;
  const int t0 = ch * 5 + (ch < 32 ? ch : 32);
  const int t1 = t0 + 5 + (ch < 32 ? 1 : 0);
  const int pos0 = *cur_pos, pos1 = pos0 + T_TOT;

  __shared__ __align__(16) unsigned short Klds[64 * 136];
  __shared__ __align__(16) unsigned short Vt[128 * 72];
  __shared__ __align__(16) unsigned short Plds[4 * 16 * 72];

  bf16x8 qf[4];
#pragma unroll
  for (int ks = 0; ks < 4; ++ks)
    qf[ks] = *(const bf16x8*)(qbf + ((size_t)(g * 4 + w) * L + (lane & 15)) * D + ks * 32 + (lane >> 4) * 8);

  f32x4 O[8];
  f32x4 zf = {0.f, 0.f, 0.f, 0.f};
#pragma unroll
  for (int j = 0; j < 8; ++j) O[j] = zf;
  float mrow[4] = {-1e30f, -1e30f, -1e30f, -1e30f};
  float lrow[4] = {0, 0, 0, 0};
  unsigned short* Pw = Plds + w * 16 * 72;

  float4 ka[4], kb[4], va[4], vb[4];
  float mrgC[16], mrgN[16];
  int pp[4];

#define LOADT(ti_) do {                                                         \
    _Pragma("unroll")                                                           \
    for (int g2 = 0; g2 < 4; ++g2) {                                            \
      int slot = tid + g2 * 256;                                                \
      int pos = slot >> 4, c0 = (slot & 15) * 8;                                \
      int p = (ti_) * 64 + pos;                                                 \
      pp[g2] = p;                                                               \
      bool u = (p >= pos0) & (p < pos1);                                        \
      const float* sp = u ? cache : kv_src;                                     \
      size_t kidx = ((size_t)g * SL + p) * D + c0;                              \
      size_t vidx = ((size_t)(NKV + g) * SL + p) * D + c0;                      \
      ka[g2] = *(const float4*)(sp + kidx);                                     \
      kb[g2] = *(const float4*)(sp + kidx + 4);                                 \
      va[g2] = *(const float4*)(sp + vidx);                                     \
      vb[g2] = *(const float4*)(sp + vidx + 4);                                 \
    }                                                                           \
    _Pragma("unroll")                                                           \
    for (int ee = 0; ee < 4; ++ee)                                              \
      _Pragma("unroll")                                                         \
      for (int nf2 = 0; nf2 < 4; ++nf2)                                         \
        mrgN[ee * 4 + nf2] = mask[(size_t)((lane >> 4) * 4 + ee) * SL +         \
                                  (ti_) * 64 + nf2 * 16 + (lane & 15)];         \
  } while (0)

#define WRITET() do {                                                           \
    _Pragma("unroll")                                                           \
    for (int g2 = 0; g2 < 4; ++g2) {                                            \
      int slot = tid + g2 * 256;                                                \
      int pos = slot >> 4, c0 = (slot & 15) * 8;                                \
      int p = pp[g2];                                                           \
      bool u = (p >= pos0) & (p < pos1);                                        \
      if (!u) {                                                                 \
        size_t kidx = ((size_t)g * SL + p) * D + c0;                            \
        size_t vidx = ((size_t)(NKV + g) * SL + p) * D + c0;                    \
        *(float4*)(cache + kidx) = ka[g2];                                      \
        *(float4*)(cache + kidx + 4) = kb[g2];                                  \
        *(float4*)(cache + vidx) = va[g2];                                      \
        *(float4*)(cache + vidx + 4) = vb[g2];                                  \
      }                                                                         \
      float kf[8] = {ka[g2].x, ka[g2].y, ka[g2].z, ka[g2].w,                    \
                     kb[g2].x, kb[g2].y, kb[g2].z, kb[g2].w};                   \
      st8lds(Klds + pos * 136 + c0, kf);                                        \
      float vf[8] = {va[g2].x, va[g2].y, va[g2].z, va[g2].w,                    \
                     vb[g2].x, vb[g2].y, vb[g2].z, vb[g2].w};                   \
      _Pragma("unroll")                                                         \
      for (int jj = 0; jj < 8; ++jj) {                                          \
        int dd = c0 + jj;                                                       \
        Vt[dd * 72 + (pos ^ (((dd >> 3) & 7) << 3))] = f2bf(vf[jj]);            \
      }                                                                         \
    }                                                                           \
  } while (0)

  LOADT(t0);
  for (int ti = t0; ti < t1; ++ti) {
    WRITET();
#pragma unroll
    for (int ii = 0; ii < 16; ++ii) mrgC[ii] = mrgN[ii];
    if (ti + 1 < t1) LOADT(ti + 1);
    lds_barrier();

    // ---- QK^T ----
    f32x4 Sv[4];
#pragma unroll
    for (int nf = 0; nf < 4; ++nf) {
      f32x4 accs = zf;
#pragma unroll
      for (int ks = 0; ks < 4; ++ks) {
        int pl = nf * 16 + (lane & 15);
        bf16x8 bk = *(const bf16x8*)(Klds + pl * 136 + ks * 32 + (lane >> 4) * 8);
        accs = __builtin_amdgcn_mfma_f32_16x16x32_bf16(qf[ks], bk, accs, 0, 0, 0);
      }
      Sv[nf] = accs;
    }

    // ---- online softmax ----
#pragma unroll
    for (int e = 0; e < 4; ++e) {
      int lq = (lane >> 4) * 4 + e;
      float sc[4];
#pragma unroll
      for (int nf = 0; nf < 4; ++nf)
        sc[nf] = Sv[nf][e] * SCALE + mrgC[e * 4 + nf];
      float tmax = fmaxf(fmaxf(sc[0], sc[1]), fmaxf(sc[2], sc[3]));
#pragma unroll
      for (int mm = 1; mm < 16; mm <<= 1) tmax = fmaxf(tmax, __shfl_xor(tmax, mm));
      float mnew = fmaxf(mrow[e], tmax);
      float alpha = __expf(mrow[e] - mnew);
      float psum = 0;
#pragma unroll
      for (int nf = 0; nf < 4; ++nf) {
        float p = __expf(sc[nf] - mnew);
        psum += p;
        Pw[lq * 72 + nf * 16 + (lane & 15)] = f2bf(p);
      }
#pragma unroll
      for (int mm = 1; mm < 16; mm <<= 1) psum += __shfl_xor(psum, mm);
      lrow[e] = lrow[e] * alpha + psum;
      mrow[e] = mnew;
#pragma unroll
      for (int j = 0; j < 8; ++j) O[j][e] *= alpha;
    }

    // ---- PV ----
#pragma unroll
    for (int ks2 = 0; ks2 < 2; ++ks2) {
      bf16x8 ap = *(const bf16x8*)(Pw + (lane & 15) * 72 + ks2 * 32 + (lane >> 4) * 8);
#pragma unroll
      for (int jf = 0; jf < 8; ++jf) {
        int dd = jf * 16 + (lane & 15);
        int po = (ks2 * 32 + (lane >> 4) * 8) ^ (((dd >> 3) & 7) << 3);
        bf16x8 bv = *(const bf16x8*)(Vt + dd * 72 + po);
        O[jf] = __builtin_amdgcn_mfma_f32_16x16x32_bf16(ap, bv, O[jf], 0, 0, 0);
      }
    }
    lds_barrier();
  }
#undef LOADT
#undef WRITET

  const int cidx = g * NCHUNK + ch;
#pragma unroll
  for (int jf = 0; jf < 8; ++jf)
#pragma unroll
    for (int e = 0; e < 4; ++e) {
      int qr = w * 16 + (lane >> 4) * 4 + e;
      part_O[((size_t)cidx * 64 + qr) * D + jf * 16 + (lane & 15)] = f2bf(O[jf][e]);
    }
  if ((lane & 15) == 0) {
#pragma unroll
    for (int e = 0; e < 4; ++e) {
      int qr = w * 16 + (lane >> 4) * 4 + e;
      part_m[cidx * 64 + qr] = mrow[e];
      part_l[cidx * 64 + qr] = lrow[e];
    }
  }
}

// ---------- combine partials (block-cooperative M/Lsum, weights cached in LDS) ----------
__global__ void k_attn_reduce(const unsigned short* __restrict__ part_O,
                              const float* __restrict__ part_m,
                              const float* __restrict__ part_l,
                              unsigned short* __restrict__ attnbf) {
  const int g = blockIdx.x >> 6;
  const int qr = blockIdx.x & 63;
  const int d = threadIdx.x;  // 128 threads
  __shared__ float Wlds[NCHUNK];
  __shared__ float rmax[2];
  __shared__ float rsum[2];

  float mv = (d < NCHUNK) ? part_m[(g * NCHUNK + d) * 64 + qr] : -1e30f;
  float t = mv;
  for (int mm = 1; mm < 64; mm <<= 1) t = fmaxf(t, __shfl_xor(t, mm));
  if ((d & 63) == 0) rmax[d >> 6] = t;
  __syncthreads();
  float M = fmaxf(rmax[0], rmax[1]);

  float wgt = (d < NCHUNK) ? __expf(mv - M) : 0.f;
  float lv = (d < NCHUNK) ? part_l[(g * NCHUNK + d) * 64 + qr] * wgt : 0.f;
  if (d < NCHUNK) Wlds[d] = wgt;
  float s = lv;
  for (int mm = 1; mm < 64; mm <<= 1) s += __shfl_xor(s, mm);
  if ((d & 63) == 0) rsum[d >> 6] = s;
  __syncthreads();
  float Lsum = rsum[0] + rsum[1];

  float acc = 0;
  for (int c = 0; c < NCHUNK; ++c)
    acc += Wlds[c] * bf2f(part_O[((size_t)(g * NCHUNK + c) * 64 + qr) * D + d]);
  float o = acc / fmaxf(Lsum, 1e-20f);
  int h = g * 4 + (qr >> 4), l = qr & 15;
  attnbf[(size_t)l * 4096 + h * 128 + d] = f2bf(o);
}

// ---------- output projection: wo read f32 directly, reg-staged ----------
__launch_bounds__(256)
__global__ void k_out_gemm(const unsigned short* __restrict__ attnbf,
                           const float* __restrict__ wo,
                           float* __restrict__ part_out) {
  const int ntile = blockIdx.x;
  const int ksp = blockIdx.y;
  const int tid = threadIdx.x, lane = tid & 63, w = tid >> 6;
  __shared__ __align__(16) unsigned char Asm[2048];
  __shared__ __align__(16) unsigned char Bsm[16384];

  f32x4 zf = {0.f, 0.f, 0.f, 0.f};
  f32x4 acc[2] = {zf, zf};
  for (int it = 0; it < 4; ++it) {
    if (w < 2) {
      int sl = w * 64 + lane;
      gl_lds16(attnbf + (size_t)(sl >> 3) * 4096 + ksp * 256 + it * 64 + (sl & 7) * 8, Asm + w * 1024);
    }
#pragma unroll
    for (int q = 0; q < 4; ++q) {
      int sl = (w * 4 + q) * 64 + lane;
      int row = sl >> 3, c0 = (sl & 7) * 8;
      float v8[8];
      ld8f(wo + (size_t)(ntile * 128 + row) * 4096 + ksp * 256 + it * 64 + c0, v8);
      st8lds((unsigned short*)Bsm + row * 64 + c0, v8);
    }
    __syncthreads();
#pragma unroll
    for (int ks = 0; ks < 2; ++ks) {
      bf16x8 a = *(const bf16x8*)(Asm + (lane & 15) * 128 + ks * 64 + (lane >> 4) * 16);
#pragma unroll
      for (int j = 0; j < 2; ++j) {
        int nr = w * 32 + j * 16 + (lane & 15);
        bf16x8 b = *(const bf16x8*)(Bsm + nr * 128 + ks * 64 + (lane >> 4) * 16);
        acc[j] = __builtin_amdgcn_mfma_f32_16x16x32_bf16(a, b, acc[j], 0, 0, 0);
      }
    }
    __syncthreads();
  }
#pragma unroll
  for (int j = 0; j < 2; ++j)
#pragma unroll
    for (int e = 0; e < 4; ++e) {
      int lq = (lane >> 4) * 4 + e;
      int n = ntile * 128 + w * 32 + j * 16 + (lane & 15);
      part_out[(size_t)ksp * 32768 + lq * 2048 + n] = acc[j][e];
    }
}

__global__ void k_out_combine(const float* __restrict__ part_out, float* __restrict__ out0) {
  int i = blockIdx.x * 256 + threadIdx.x;
  if (i < 32768) {
    float v = 0;
    for (int c = 0; c < 16; ++c) v += part_out[c * 32768 + i];
    out0[i] = v;
  }
}

extern "C" void kernel_launch(void* const* d_in, const int* in_sizes, int n_in,
                              void* d_out, int out_size, void* d_ws, size_t ws_size,
                              hipStream_t stream) {
  const float* x     = (const float*)d_in[0];
  const float* x_ctx = (const float*)d_in[1];
  const float* cos_q = (const float*)d_in[2];
  const float* sin_q = (const float*)d_in[3];
  const float* cos_k = (const float*)d_in[4];
  const float* sin_k = (const float*)d_in[5];
  const float* kv    = (const float*)d_in[6];
  const float* mask  = (const float*)d_in[7];
  const float* wq    = (const float*)d_in[8];
  const float* wk    = (const float*)d_in[9];
  const float* wv    = (const float*)d_in[10];
  const float* wo    = (const float*)d_in[11];
  const float* qn_w  = (const float*)d_in[12];
  const float* kn_w  = (const float*)d_in[13];
  const int* cur_pos = (const int*)d_in[14];

  float* out0 = (float*)d_out;
  float* cache = out0 + 32768;

  uint8_t* ws = (uint8_t*)d_ws;
  unsigned short* xc_bf  = (unsigned short*)(ws);               // 0x810000
  unsigned short* wk_bf  = (unsigned short*)(ws + 0x0810000);   // 0x400000
  unsigned short* wv_bf  = (unsigned short*)(ws + 0x0C10000);   // 0x400000
  float* qpart           = (float*)(ws + 0x1010000);            // 0x400000
  unsigned short* qbf    = (unsigned short*)(ws + 0x1410000);   // 0x20000
  unsigned short* attnbf = (unsigned short*)(ws + 0x1430000);   // 0x20000
  unsigned short* part_O = (unsigned short*)(ws + 0x1450000);   // 0xC00000
  float* part_m          = (float*)(ws + 0x2050000);            // 0x30000
  float* part_l          = (float*)(ws + 0x2090000);            // 0x30000
  float* part_out        = (float*)(ws + 0x20D0000);            // 0x200000

  unsigned short* xq_bf = xc_bf + (size_t)2048 * H;

  k_conv<<<dim3(4112), dim3(256), 0, stream>>>(wk, wv, x_ctx, x, wk_bf, wv_bf, xc_bf);
  k_q_proj<<<dim3(32, 16), dim3(256), 0, stream>>>(xq_bf, wq, qpart);
  k_q_fin<<<dim3(512), dim3(128), 0, stream>>>(qpart, qn_w, cos_q, sin_q, qbf);
  k_kv_gemm<<<dim3(16, 33), dim3(256), 0, stream>>>(xc_bf, wk_bf, wv_bf, kn_w, cos_k, sin_k, cur_pos, cache);
  k_attn<<<dim3(8, NCHUNK), dim3(256), 0, stream>>>(kv, cache, qbf, mask, cur_pos, part_O, part_m, part_l);
  k_attn_reduce<<<dim3(512), dim3(128), 0, stream>>>(part_O, part_m, part_l, attnbf);
  k_out_gemm<<<dim3(16, 16), dim3(256), 0, stream>>>(attnbf, wo, part_out);
  k_out_combine<<<dim3(128), dim3(256), 0, stream>>>(part_out, out0);
}